// Round 10
// baseline (81.182 us; speedup 1.0000x reference)
//
#include <hip/hip_runtime.h>

typedef __bf16 bf16x8 __attribute__((ext_vector_type(8)));
typedef float f32x4 __attribute__((ext_vector_type(4)));

#define DEV static __device__ __forceinline__

DEV unsigned short f2b(float f){
    unsigned int u = __float_as_uint(f);
    u += 0x7fffu + ((u >> 16) & 1u);
    return (unsigned short)(u >> 16);
}
DEV float b2f(unsigned short h){ return __uint_as_float(((unsigned int)h) << 16); }
DEV float blo(unsigned int u){ return __uint_as_float(u << 16); }
DEV float bhi(unsigned int u){ return __uint_as_float(u & 0xffff0000u); }
DEV float gelu_f(float x){ return 0.5f * x * (1.0f + erff(x * 0.7071067811865476f)); }

// async global->LDS, 16B per lane, wave-uniform LDS base (HW adds lane*16).
DEV void gload16(const unsigned short* g, unsigned short* l){
    __builtin_amdgcn_global_load_lds(
        (const __attribute__((address_space(1))) void*)g,
        (__attribute__((address_space(3))) void*)l, 16, 0, 0);
}

// ---------------------------------------------------------------- constants
static constexpr int NROW = 8192;   // B*D*H*W = 2*16*16*16
static constexpr int C    = 256;
static constexpr int F    = 1024;
static constexpr float ATT_SCALE = 0.17677669529663688f;   // 1/sqrt(32)

// ---------------------------------------------------------------- prep + LN1
__global__ __launch_bounds__(256)
void prep_ln_kernel(const float* __restrict__ Wq, const float* __restrict__ Wk,
                    const float* __restrict__ Wv, const float* __restrict__ Wo,
                    const float* __restrict__ W1, const float* __restrict__ W2,
                    const float* __restrict__ bq, const float* __restrict__ bk,
                    const float* __restrict__ bv,
                    unsigned short* __restrict__ WQT, unsigned short* __restrict__ WKT,
                    unsigned short* __restrict__ WVT, unsigned short* __restrict__ WOT,
                    unsigned short* __restrict__ W1T, unsigned short* __restrict__ W2T,
                    float* __restrict__ bqkv,
                    const float* __restrict__ x, const float* __restrict__ g1,
                    const float* __restrict__ b1,
                    unsigned short* __restrict__ tn, unsigned short* __restrict__ xb)
{
    const int tid = threadIdx.x;
    if (blockIdx.x < 192) {
        __shared__ unsigned short T[64][66];
        const int t = blockIdx.x;
        const float* src; unsigned short* dst;
        int ldw, ldt, r0, c0; float sc = 1.0f;
        if (t < 64) {                       // 4 square 256x256 mats, 16 tiles each
            const int m = t >> 4, sub = t & 15;
            src = (m == 0) ? Wq : (m == 1) ? Wk : (m == 2) ? Wv : Wo;
            dst = (m == 0) ? WQT : (m == 1) ? WKT : (m == 2) ? WVT : WOT;
            if (m == 0) sc = ATT_SCALE;
            ldw = 256; ldt = 256;
            r0 = (sub >> 2) * 64; c0 = (sub & 3) * 64;
        } else if (t < 128) {               // W1: 256x1024 -> W1T [1024][256]
            const int sub = t - 64;
            src = W1; dst = W1T; ldw = 1024; ldt = 256;
            r0 = (sub >> 4) * 64; c0 = (sub & 15) * 64;
        } else {                            // W2: 1024x256 -> W2T [256][1024]
            const int sub = t - 128;
            src = W2; dst = W2T; ldw = 256; ldt = 1024;
            r0 = (sub >> 2) * 64; c0 = (sub & 3) * 64;
        }
        #pragma unroll
        for (int i = 0; i < 16; ++i) {
            const int rl = i * 4 + (tid >> 6), cl = tid & 63;
            T[rl][cl] = f2b(src[(size_t)(r0 + rl) * ldw + c0 + cl] * sc);
        }
        __syncthreads();
        #pragma unroll
        for (int j = 0; j < 16; ++j) {
            const int cl = j * 4 + (tid >> 6), rl = tid & 63;
            dst[(size_t)(c0 + cl) * ldt + r0 + rl] = T[rl][cl];
        }
    } else if (blockIdx.x == 192) {
        #pragma unroll
        for (int i = 0; i < 3; ++i) {
            const int v = i * 256 + tid;
            bqkv[v] = (v < 256) ? bq[v] * ATT_SCALE
                    : (v < 512) ? bk[v - 256] : bv[v - 512];
        }
    } else {
        const int row  = (blockIdx.x - 193) * 4 + (tid >> 6);
        const int lane = tid & 63;
        float4 v = ((const float4*)(x + (size_t)row * C))[lane];
        float s = v.x + v.y + v.z + v.w;
        #pragma unroll
        for (int m = 32; m >= 1; m >>= 1) s += __shfl_xor(s, m);
        const float mean = s * (1.0f / 256.0f);
        const float d0 = v.x - mean, d1 = v.y - mean, d2 = v.z - mean, d3 = v.w - mean;
        float s2 = d0 * d0 + d1 * d1 + d2 * d2 + d3 * d3;
        #pragma unroll
        for (int m = 32; m >= 1; m >>= 1) s2 += __shfl_xor(s2, m);
        const float rstd = rsqrtf(s2 * (1.0f / 256.0f) + 1e-5f);
        float4 gg = ((const float4*)g1)[lane];
        float4 bb = ((const float4*)b1)[lane];
        ushort4 o = { f2b(d0 * rstd * gg.x + bb.x), f2b(d1 * rstd * gg.y + bb.y),
                      f2b(d2 * rstd * gg.z + bb.z), f2b(d3 * rstd * gg.w + bb.w) };
        ((ushort4*)(tn + (size_t)row * C))[lane] = o;
        ushort4 xo = { f2b(v.x), f2b(v.y), f2b(v.z), f2b(v.w) };
        ((ushort4*)(xb + (size_t)row * C))[lane] = xo;
    }
}

// ---------------------------------------------------------------- LN2
__global__ __launch_bounds__(256)
void ln_kernel(const float* __restrict__ X, const float* __restrict__ g,
               const float* __restrict__ bta, unsigned short* __restrict__ OUT)
{
    const int row  = blockIdx.x * 4 + (threadIdx.x >> 6);
    const int lane = threadIdx.x & 63;
    float4 v = ((const float4*)(X + (size_t)row * C))[lane];
    float s = v.x + v.y + v.z + v.w;
    #pragma unroll
    for (int m = 32; m >= 1; m >>= 1) s += __shfl_xor(s, m);
    const float mean = s * (1.0f / 256.0f);
    const float d0 = v.x - mean, d1 = v.y - mean, d2 = v.z - mean, d3 = v.w - mean;
    float s2 = d0 * d0 + d1 * d1 + d2 * d2 + d3 * d3;
    #pragma unroll
    for (int m = 32; m >= 1; m >>= 1) s2 += __shfl_xor(s2, m);
    const float rstd = rsqrtf(s2 * (1.0f / 256.0f) + 1e-5f);
    float4 gg = ((const float4*)g)[lane];
    float4 bb = ((const float4*)bta)[lane];
    ushort4 o = { f2b(d0 * rstd * gg.x + bb.x), f2b(d1 * rstd * gg.y + bb.y),
                  f2b(d2 * rstd * gg.z + bb.z), f2b(d3 * rstd * gg.w + bb.w) };
    ((ushort4*)(OUT + (size_t)row * C))[lane] = o;
}

// ---------------------------------------------------------------- 64x64 GEMM
// BK=64, 4 waves, dbuf LDS via gload_lds w16 (wave-uniform LDS base),
// XOR swizzle (rule #21): inverse-swizzled global src chunk + swizzled ds_read.
template<int K, int MODE>
DEV void gemm_body(const unsigned short* __restrict__ A, int m0,
                   const unsigned short* __restrict__ BTt,
                   const float* __restrict__ biast,
                   const float* __restrict__ res, void* __restrict__ outp,
                   int ldo, int ocol0,
                   unsigned short (&As)[2][4096], unsigned short (&Bs)[2][4096])
{
    constexpr int BK = 64, NKT = K / BK;
    const int tid  = threadIdx.x;
    const int lane = tid & 63, wid = tid >> 6;
    const int srow = tid >> 3;                    // 0..31
    const int schk = (tid & 7) ^ (srow & 7);      // inverse-swizzled src chunk

    const unsigned short* Ag = A   + (size_t)(m0 + srow) * K + schk * 8;
    const unsigned short* Bg = BTt + (size_t)srow        * K + schk * 8;

    const int wbase = __builtin_amdgcn_readfirstlane(wid) * 512;

    gload16(Ag,          &As[0][wbase]);
    gload16(Ag + 32 * K, &As[0][wbase + 2048]);
    gload16(Bg,          &Bs[0][wbase]);
    gload16(Bg + 32 * K, &Bs[0][wbase + 2048]);
    __syncthreads();

    f32x4 acc[4] = {};
    const int lr = lane & 15, lk = lane >> 4;
    const int sw = lr & 7;

    for (int kt = 0; kt < NKT; ++kt) {
        if (kt + 1 < NKT) {
            const int nb = (kt + 1) & 1;
            gload16(Ag + (kt + 1) * BK,          &As[nb][wbase]);
            gload16(Ag + 32 * K + (kt + 1) * BK, &As[nb][wbase + 2048]);
            gload16(Bg + (kt + 1) * BK,          &Bs[nb][wbase]);
            gload16(Bg + 32 * K + (kt + 1) * BK, &Bs[nb][wbase + 2048]);
        }
        const unsigned short* as = As[kt & 1];
        const unsigned short* bs = Bs[kt & 1];
        #pragma unroll
        for (int s = 0; s < 2; ++s) {
            const int c16 = (s * 4 + lk) ^ sw;
            bf16x8 bfr = *reinterpret_cast<const bf16x8*>(&bs[(wid * 16 + lr) * 64 + c16 * 8]);
            #pragma unroll
            for (int m = 0; m < 4; ++m) {
                bf16x8 afr = *reinterpret_cast<const bf16x8*>(&as[(m * 16 + lr) * 64 + c16 * 8]);
                acc[m] = __builtin_amdgcn_mfma_f32_16x16x32_bf16(afr, bfr, acc[m], 0, 0, 0);
            }
        }
        if (kt + 1 < NKT) __syncthreads();
    }

    const int col  = ocol0 + wid * 16 + lr;
    const float bcol = biast[wid * 16 + lr];
    #pragma unroll
    for (int m = 0; m < 4; ++m) {
        #pragma unroll
        for (int r = 0; r < 4; ++r) {
            const int row = m0 + m * 16 + lk * 4 + r;
            float v = acc[m][r] + bcol;
            if (MODE == 0) {
                ((unsigned short*)outp)[(size_t)row * ldo + col] = f2b(v);
            } else if (MODE == 1) {
                ((unsigned short*)outp)[(size_t)row * ldo + col] = f2b(gelu_f(v));
            } else {
                v += res[(size_t)row * ldo + col];
                ((float*)outp)[(size_t)row * ldo + col] = v;
            }
        }
    }
}

// XCD-swizzled 1D-grid tile map, column-fastest (T1). Requires nwg % 8 == 0.
template<int NC, int TS>
DEV void tile_map(int& m0, int& n0){
    const int nwg = gridDim.x;
    const int lin = blockIdx.x;
    const int tile = (lin & 7) * (nwg >> 3) + (lin >> 3);
    m0 = (tile / NC) * TS;
    n0 = (tile % NC) * TS;
}

// Fused Q/K/V GEMM: N=768 packed output, A = tn for Q cols, xb for K/V cols.
__global__ __launch_bounds__(256)
void qkv_kernel(const unsigned short* __restrict__ tn,
                const unsigned short* __restrict__ xb,
                const unsigned short* __restrict__ WT,    // [768][256]
                const float* __restrict__ bqkv,           // [768]
                unsigned short* __restrict__ QKV)         // [8192][768]
{
    __shared__ unsigned short As[2][4096], Bs[2][4096];
    int m0, n0; tile_map<12, 64>(m0, n0);
    const unsigned short* A = (n0 < 256) ? tn : xb;
    gemm_body<256, 0>(A, m0, WT + (size_t)n0 * 256,
                      bqkv + n0, nullptr, QKV, 768, n0, As, Bs);
}

template<int K, int MODE, int NC>
__global__ __launch_bounds__(256)
void gemm_kernel(const unsigned short* __restrict__ A,
                 const unsigned short* __restrict__ BT,
                 const float* __restrict__ bias,
                 const float* __restrict__ res,
                 void* __restrict__ outp, int ldo)
{
    __shared__ unsigned short As[2][4096], Bs[2][4096];
    int m0, n0; tile_map<NC, 64>(m0, n0);
    gemm_body<K, MODE>(A, m0, BT + (size_t)n0 * K,
                       bias + n0, res, outp, ldo, n0, As, Bs);
}

// ---------------------------------------------------------------- attention
// Thread = (voxel, head, quarter): 8 channels per thread, 4 lanes per head.
// 262144 threads -> 1024 blocks -> 4 blocks/CU -> 16 waves/CU (~50% occ),
// vs round-9's 1 wave/SIMD (10%). The 32-ch dot needs only a 4-lane reduce:
// 2x shfl_xor (masks 1,2 = quad-perm DPP = VALU pipe, not LDS).
// No branches: invalid neighbors read own row, score -inf -> p = 0.
// QKV layout: [NROW][768] bf16: Q (pre-scaled) 0..255, K 256..511, V 512..767.
DEV float dot8(uint4 u, const float* q){
    float s;
    s = q[0] * blo(u.x);          s = fmaf(q[1], bhi(u.x), s);
    s = fmaf(q[2], blo(u.y), s);  s = fmaf(q[3], bhi(u.y), s);
    s = fmaf(q[4], blo(u.z), s);  s = fmaf(q[5], bhi(u.z), s);
    s = fmaf(q[6], blo(u.w), s);  s = fmaf(q[7], bhi(u.w), s);
    return s;
}

__global__ __launch_bounds__(256, 4)
void attn_kernel(const unsigned short* __restrict__ QKV,
                 unsigned short* __restrict__ AO)
{
    const int t   = blockIdx.x * 256 + threadIdx.x;
    const int vox = t >> 5;                 // 32 threads per voxel
    const int ch  = (t & 31) * 8;           // head*32 + quarter*8
    const int d = (vox >> 8) & 15, h = (vox >> 4) & 15, w = vox & 15;

    float q[8];
    {
        uint4 u = *reinterpret_cast<const uint4*>(&QKV[(size_t)vox * 768 + ch]);
        q[0]=blo(u.x); q[1]=bhi(u.x); q[2]=blo(u.y); q[3]=bhi(u.y);
        q[4]=blo(u.z); q[5]=bhi(u.z); q[6]=blo(u.w); q[7]=bhi(u.w);
    }

    float sc[27];
    int   nr[27];
    #pragma unroll
    for (int kk = 0; kk < 27; ++kk) {
        const int di = kk / 9 - 1, hi2 = (kk / 3) % 3 - 1, wi = kk % 3 - 1;
        const int nd = d + di, nh = h + hi2, nw = w + wi;
        const bool valid = (kk != 13) && ((unsigned)nd < 16u) &&
                           ((unsigned)nh < 16u) && ((unsigned)nw < 16u);
        const int r = valid ? ((vox & 4096) | (nd << 8) | (nh << 4) | nw) : vox;
        nr[kk] = r;
        uint4 u = *reinterpret_cast<const uint4*>(&QKV[(size_t)r * 768 + 256 + ch]);
        float s = dot8(u, q);
        s += __shfl_xor(s, 1);              // quad-perm DPP (VALU), 4-lane reduce
        s += __shfl_xor(s, 2);
        sc[kk] = valid ? s : -INFINITY;
    }

    float mx = sc[0];
    #pragma unroll
    for (int kk = 1; kk < 27; ++kk) mx = fmaxf(mx, sc[kk]);
    float z = 0.0f;
    #pragma unroll
    for (int kk = 0; kk < 27; ++kk) { float p = __expf(sc[kk] - mx); sc[kk] = p; z += p; }
    const float inv = 1.0f / z;

    float acc[8] = {};
    #pragma unroll
    for (int kk = 0; kk < 27; ++kk) {
        uint4 u = *reinterpret_cast<const uint4*>(&QKV[(size_t)nr[kk] * 768 + 512 + ch]);
        const float p = sc[kk];
        acc[0] = fmaf(p, blo(u.x), acc[0]); acc[1] = fmaf(p, bhi(u.x), acc[1]);
        acc[2] = fmaf(p, blo(u.y), acc[2]); acc[3] = fmaf(p, bhi(u.y), acc[3]);
        acc[4] = fmaf(p, blo(u.z), acc[4]); acc[5] = fmaf(p, bhi(u.z), acc[5]);
        acc[6] = fmaf(p, blo(u.w), acc[6]); acc[7] = fmaf(p, bhi(u.w), acc[7]);
    }

    uint4 o;
    o.x = (unsigned)f2b(acc[0] * inv) | ((unsigned)f2b(acc[1] * inv) << 16);
    o.y = (unsigned)f2b(acc[2] * inv) | ((unsigned)f2b(acc[3] * inv) << 16);
    o.z = (unsigned)f2b(acc[4] * inv) | ((unsigned)f2b(acc[5] * inv) << 16);
    o.w = (unsigned)f2b(acc[6] * inv) | ((unsigned)f2b(acc[7] * inv) << 16);
    *reinterpret_cast<uint4*>(&AO[(size_t)vox * C + ch]) = o;
}

// ---------------------------------------------------------------- launch
extern "C" void kernel_launch(void* const* d_in, const int* in_sizes, int n_in,
                              void* d_out, int out_size, void* d_ws, size_t ws_size,
                              hipStream_t stream)
{
    const float* x   = (const float*)d_in[0];
    const float* Wq  = (const float*)d_in[1];
    const float* bq  = (const float*)d_in[2];
    const float* Wk  = (const float*)d_in[3];
    const float* bk  = (const float*)d_in[4];
    const float* Wv  = (const float*)d_in[5];
    const float* bv  = (const float*)d_in[6];
    const float* Wo  = (const float*)d_in[7];
    const float* bo  = (const float*)d_in[8];
    const float* g1  = (const float*)d_in[9];
    const float* b1  = (const float*)d_in[10];
    const float* g2  = (const float*)d_in[11];
    const float* b2  = (const float*)d_in[12];
    const float* W1  = (const float*)d_in[13];
    const float* bf1 = (const float*)d_in[14];
    const float* W2  = (const float*)d_in[15];
    const float* bf2 = (const float*)d_in[16];

    char* ws = (char*)d_ws;
    size_t o = 0;
    unsigned short* WQT = (unsigned short*)(ws + o); o += (size_t)256 * 256 * 2;   // [768][256] with WKT/WVT
    unsigned short* WKT = (unsigned short*)(ws + o); o += (size_t)256 * 256 * 2;
    unsigned short* WVT = (unsigned short*)(ws + o); o += (size_t)256 * 256 * 2;
    unsigned short* WOT = (unsigned short*)(ws + o); o += (size_t)256 * 256 * 2;
    unsigned short* W1T = (unsigned short*)(ws + o); o += (size_t)256 * 1024 * 2;
    unsigned short* W2T = (unsigned short*)(ws + o); o += (size_t)1024 * 256 * 2;
    float*          bqkv= (float*)(ws + o);          o += (size_t)768 * 4;
    unsigned short* tn  = (unsigned short*)(ws + o); o += (size_t)NROW * C * 2;
    unsigned short* xb  = (unsigned short*)(ws + o); o += (size_t)NROW * C * 2;
    unsigned short* QKVb= (unsigned short*)(ws + o); o += (size_t)NROW * 768 * 2;
    unsigned short* AOb = (unsigned short*)(ws + o); o += (size_t)NROW * C * 2;
    float*          Tf  = (float*)(ws + o);          o += (size_t)NROW * C * 4;
    unsigned short* tn2 = (unsigned short*)(ws + o); o += (size_t)NROW * C * 2;
    unsigned short* Hb  = (unsigned short*)(ws + o); o += (size_t)NROW * F * 2;

    prep_ln_kernel<<<193 + NROW / 4, 256, 0, stream>>>(Wq, Wk, Wv, Wo, W1, W2, bq, bk, bv,
                                                       WQT, WKT, WVT, WOT, W1T, W2T, bqkv,
                                                       x, g1, b1, tn, xb);

    qkv_kernel<<<(NROW / 64) * 12, 256, 0, stream>>>(tn, xb, WQT, bqkv, QKVb);

    attn_kernel<<<NROW * 32 / 256, 256, 0, stream>>>(QKVb, AOb);

    gemm_kernel<256, 2, 4><<<(NROW / 64) * 4, 256, 0, stream>>>(AOb, WOT, bo, x, Tf, 256);

    ln_kernel<<<NROW / 4, 256, 0, stream>>>(Tf, g2, b2, tn2);

    gemm_kernel<256, 1, 16><<<(NROW / 64) * 16, 256, 0, stream>>>(tn2, W1T, bf1, nullptr, Hb, 1024);

    gemm_kernel<1024, 2, 4><<<(NROW / 64) * 4, 256, 0, stream>>>(Hb, W2T, bf2, Tf, (float*)d_out, 256);
}

// Round 11
// 79.782 us; speedup vs baseline: 1.0176x; 1.0176x over previous
//
#include <hip/hip_runtime.h>

typedef __bf16 bf16x8 __attribute__((ext_vector_type(8)));
typedef float f32x4 __attribute__((ext_vector_type(4)));

#define DEV static __device__ __forceinline__

DEV unsigned short f2b(float f){
    unsigned int u = __float_as_uint(f);
    u += 0x7fffu + ((u >> 16) & 1u);
    return (unsigned short)(u >> 16);
}
DEV float b2f(unsigned short h){ return __uint_as_float(((unsigned int)h) << 16); }
DEV float blo(unsigned int u){ return __uint_as_float(u << 16); }
DEV float bhi(unsigned int u){ return __uint_as_float(u & 0xffff0000u); }
DEV float gelu_f(float x){ return 0.5f * x * (1.0f + erff(x * 0.7071067811865476f)); }

// async global->LDS, 16B per lane, wave-uniform LDS base (HW adds lane*16).
DEV void gload16(const unsigned short* g, unsigned short* l){
    __builtin_amdgcn_global_load_lds(
        (const __attribute__((address_space(1))) void*)g,
        (__attribute__((address_space(3))) void*)l, 16, 0, 0);
}

// ---------------------------------------------------------------- constants
static constexpr int NROW = 8192;   // B*D*H*W = 2*16*16*16
static constexpr int C    = 256;
static constexpr int F    = 1024;
static constexpr float ATT_SCALE = 0.17677669529663688f;   // 1/sqrt(32)

// ---------------------------------------------------------------- prep + LN1
__global__ __launch_bounds__(256)
void prep_ln_kernel(const float* __restrict__ Wq, const float* __restrict__ Wk,
                    const float* __restrict__ Wv, const float* __restrict__ Wo,
                    const float* __restrict__ W1, const float* __restrict__ W2,
                    const float* __restrict__ bq, const float* __restrict__ bk,
                    const float* __restrict__ bv,
                    unsigned short* __restrict__ WQT, unsigned short* __restrict__ WKT,
                    unsigned short* __restrict__ WVT, unsigned short* __restrict__ WOT,
                    unsigned short* __restrict__ W1T, unsigned short* __restrict__ W2T,
                    float* __restrict__ bqkv,
                    const float* __restrict__ x, const float* __restrict__ g1,
                    const float* __restrict__ b1,
                    unsigned short* __restrict__ tn, unsigned short* __restrict__ xb)
{
    const int tid = threadIdx.x;
    if (blockIdx.x < 192) {
        __shared__ unsigned short T[64][66];
        const int t = blockIdx.x;
        const float* src; unsigned short* dst;
        int ldw, ldt, r0, c0; float sc = 1.0f;
        if (t < 64) {                       // 4 square 256x256 mats, 16 tiles each
            const int m = t >> 4, sub = t & 15;
            src = (m == 0) ? Wq : (m == 1) ? Wk : (m == 2) ? Wv : Wo;
            dst = (m == 0) ? WQT : (m == 1) ? WKT : (m == 2) ? WVT : WOT;
            if (m == 0) sc = ATT_SCALE;
            ldw = 256; ldt = 256;
            r0 = (sub >> 2) * 64; c0 = (sub & 3) * 64;
        } else if (t < 128) {               // W1: 256x1024 -> W1T [1024][256]
            const int sub = t - 64;
            src = W1; dst = W1T; ldw = 1024; ldt = 256;
            r0 = (sub >> 4) * 64; c0 = (sub & 15) * 64;
        } else {                            // W2: 1024x256 -> W2T [256][1024]
            const int sub = t - 128;
            src = W2; dst = W2T; ldw = 256; ldt = 1024;
            r0 = (sub >> 2) * 64; c0 = (sub & 3) * 64;
        }
        #pragma unroll
        for (int i = 0; i < 16; ++i) {
            const int rl = i * 4 + (tid >> 6), cl = tid & 63;
            T[rl][cl] = f2b(src[(size_t)(r0 + rl) * ldw + c0 + cl] * sc);
        }
        __syncthreads();
        #pragma unroll
        for (int j = 0; j < 16; ++j) {
            const int cl = j * 4 + (tid >> 6), rl = tid & 63;
            dst[(size_t)(c0 + cl) * ldt + r0 + rl] = T[rl][cl];
        }
    } else if (blockIdx.x == 192) {
        #pragma unroll
        for (int i = 0; i < 3; ++i) {
            const int v = i * 256 + tid;
            bqkv[v] = (v < 256) ? bq[v] * ATT_SCALE
                    : (v < 512) ? bk[v - 256] : bv[v - 512];
        }
    } else {
        const int row  = (blockIdx.x - 193) * 4 + (tid >> 6);
        const int lane = tid & 63;
        float4 v = ((const float4*)(x + (size_t)row * C))[lane];
        float s = v.x + v.y + v.z + v.w;
        #pragma unroll
        for (int m = 32; m >= 1; m >>= 1) s += __shfl_xor(s, m);
        const float mean = s * (1.0f / 256.0f);
        const float d0 = v.x - mean, d1 = v.y - mean, d2 = v.z - mean, d3 = v.w - mean;
        float s2 = d0 * d0 + d1 * d1 + d2 * d2 + d3 * d3;
        #pragma unroll
        for (int m = 32; m >= 1; m >>= 1) s2 += __shfl_xor(s2, m);
        const float rstd = rsqrtf(s2 * (1.0f / 256.0f) + 1e-5f);
        float4 gg = ((const float4*)g1)[lane];
        float4 bb = ((const float4*)b1)[lane];
        ushort4 o = { f2b(d0 * rstd * gg.x + bb.x), f2b(d1 * rstd * gg.y + bb.y),
                      f2b(d2 * rstd * gg.z + bb.z), f2b(d3 * rstd * gg.w + bb.w) };
        ((ushort4*)(tn + (size_t)row * C))[lane] = o;
        ushort4 xo = { f2b(v.x), f2b(v.y), f2b(v.z), f2b(v.w) };
        ((ushort4*)(xb + (size_t)row * C))[lane] = xo;
    }
}

// ---------------------------------------------------------------- LN2
__global__ __launch_bounds__(256)
void ln_kernel(const float* __restrict__ X, const float* __restrict__ g,
               const float* __restrict__ bta, unsigned short* __restrict__ OUT)
{
    const int row  = blockIdx.x * 4 + (threadIdx.x >> 6);
    const int lane = threadIdx.x & 63;
    float4 v = ((const float4*)(X + (size_t)row * C))[lane];
    float s = v.x + v.y + v.z + v.w;
    #pragma unroll
    for (int m = 32; m >= 1; m >>= 1) s += __shfl_xor(s, m);
    const float mean = s * (1.0f / 256.0f);
    const float d0 = v.x - mean, d1 = v.y - mean, d2 = v.z - mean, d3 = v.w - mean;
    float s2 = d0 * d0 + d1 * d1 + d2 * d2 + d3 * d3;
    #pragma unroll
    for (int m = 32; m >= 1; m >>= 1) s2 += __shfl_xor(s2, m);
    const float rstd = rsqrtf(s2 * (1.0f / 256.0f) + 1e-5f);
    float4 gg = ((const float4*)g)[lane];
    float4 bb = ((const float4*)bta)[lane];
    ushort4 o = { f2b(d0 * rstd * gg.x + bb.x), f2b(d1 * rstd * gg.y + bb.y),
                  f2b(d2 * rstd * gg.z + bb.z), f2b(d3 * rstd * gg.w + bb.w) };
    ((ushort4*)(OUT + (size_t)row * C))[lane] = o;
}

// ---------------------------------------------------------------- 64x64 GEMM
// BK=64, 4 waves, dbuf LDS via gload_lds w16 (wave-uniform LDS base),
// XOR swizzle (rule #21): inverse-swizzled global src chunk + swizzled ds_read.
template<int K, int MODE>
DEV void gemm_body(const unsigned short* __restrict__ A, int m0,
                   const unsigned short* __restrict__ BTt,
                   const float* __restrict__ biast,
                   const float* __restrict__ res, void* __restrict__ outp,
                   int ldo, int ocol0,
                   unsigned short (&As)[2][4096], unsigned short (&Bs)[2][4096])
{
    constexpr int BK = 64, NKT = K / BK;
    const int tid  = threadIdx.x;
    const int lane = tid & 63, wid = tid >> 6;
    const int srow = tid >> 3;                    // 0..31
    const int schk = (tid & 7) ^ (srow & 7);      // inverse-swizzled src chunk

    const unsigned short* Ag = A   + (size_t)(m0 + srow) * K + schk * 8;
    const unsigned short* Bg = BTt + (size_t)srow        * K + schk * 8;

    const int wbase = __builtin_amdgcn_readfirstlane(wid) * 512;

    gload16(Ag,          &As[0][wbase]);
    gload16(Ag + 32 * K, &As[0][wbase + 2048]);
    gload16(Bg,          &Bs[0][wbase]);
    gload16(Bg + 32 * K, &Bs[0][wbase + 2048]);
    __syncthreads();

    f32x4 acc[4] = {};
    const int lr = lane & 15, lk = lane >> 4;
    const int sw = lr & 7;

    for (int kt = 0; kt < NKT; ++kt) {
        if (kt + 1 < NKT) {
            const int nb = (kt + 1) & 1;
            gload16(Ag + (kt + 1) * BK,          &As[nb][wbase]);
            gload16(Ag + 32 * K + (kt + 1) * BK, &As[nb][wbase + 2048]);
            gload16(Bg + (kt + 1) * BK,          &Bs[nb][wbase]);
            gload16(Bg + 32 * K + (kt + 1) * BK, &Bs[nb][wbase + 2048]);
        }
        const unsigned short* as = As[kt & 1];
        const unsigned short* bs = Bs[kt & 1];
        #pragma unroll
        for (int s = 0; s < 2; ++s) {
            const int c16 = (s * 4 + lk) ^ sw;
            bf16x8 bfr = *reinterpret_cast<const bf16x8*>(&bs[(wid * 16 + lr) * 64 + c16 * 8]);
            #pragma unroll
            for (int m = 0; m < 4; ++m) {
                bf16x8 afr = *reinterpret_cast<const bf16x8*>(&as[(m * 16 + lr) * 64 + c16 * 8]);
                acc[m] = __builtin_amdgcn_mfma_f32_16x16x32_bf16(afr, bfr, acc[m], 0, 0, 0);
            }
        }
        if (kt + 1 < NKT) __syncthreads();
    }

    const int col  = ocol0 + wid * 16 + lr;
    const float bcol = biast[wid * 16 + lr];
    #pragma unroll
    for (int m = 0; m < 4; ++m) {
        #pragma unroll
        for (int r = 0; r < 4; ++r) {
            const int row = m0 + m * 16 + lk * 4 + r;
            float v = acc[m][r] + bcol;
            if (MODE == 0) {
                ((unsigned short*)outp)[(size_t)row * ldo + col] = f2b(v);
            } else if (MODE == 1) {
                ((unsigned short*)outp)[(size_t)row * ldo + col] = f2b(gelu_f(v));
            } else {
                v += res[(size_t)row * ldo + col];
                ((float*)outp)[(size_t)row * ldo + col] = v;
            }
        }
    }
}

// XCD-swizzled 1D-grid tile map, column-fastest (T1). Requires nwg % 8 == 0.
template<int NC, int TS>
DEV void tile_map(int& m0, int& n0){
    const int nwg = gridDim.x;
    const int lin = blockIdx.x;
    const int tile = (lin & 7) * (nwg >> 3) + (lin >> 3);
    m0 = (tile / NC) * TS;
    n0 = (tile % NC) * TS;
}

// Fused Q/K/V GEMM: N=768 packed output, A = tn for Q cols, xb for K/V cols.
__global__ __launch_bounds__(256)
void qkv_kernel(const unsigned short* __restrict__ tn,
                const unsigned short* __restrict__ xb,
                const unsigned short* __restrict__ WT,    // [768][256]
                const float* __restrict__ bqkv,           // [768]
                unsigned short* __restrict__ QKV)         // [8192][768]
{
    __shared__ unsigned short As[2][4096], Bs[2][4096];
    int m0, n0; tile_map<12, 64>(m0, n0);
    const unsigned short* A = (n0 < 256) ? tn : xb;
    gemm_body<256, 0>(A, m0, WT + (size_t)n0 * 256,
                      bqkv + n0, nullptr, QKV, 768, n0, As, Bs);
}

template<int K, int MODE, int NC>
__global__ __launch_bounds__(256)
void gemm_kernel(const unsigned short* __restrict__ A,
                 const unsigned short* __restrict__ BT,
                 const float* __restrict__ bias,
                 const float* __restrict__ res,
                 void* __restrict__ outp, int ldo)
{
    __shared__ unsigned short As[2][4096], Bs[2][4096];
    int m0, n0; tile_map<NC, 64>(m0, n0);
    gemm_body<K, MODE>(A, m0, BT + (size_t)n0 * K,
                       bias + n0, res, outp, ldo, n0, As, Bs);
}

// ---------------------------------------------------------------- attention
// Thread = (voxel, head, quarter): 8 channels/thread, 4 lanes/head, 16 waves/CU.
// BATCHED MLP: loads issued in groups of 9 into registers BEFORE consumption
// (raises outstanding loads/thread from ~3 to 9 -> latency-hiding via ILP,
// round-10 lesson: occupancy alone left the gather latency-bound).
// Validity via bitmask select, no branches. 4-lane reduce = 2 DPP shfl (VALU).
// QKV layout: [NROW][768] bf16: Q (pre-scaled) 0..255, K 256..511, V 512..767.
DEV float dot8(uint4 u, const float* q){
    float s;
    s = q[0] * blo(u.x);          s = fmaf(q[1], bhi(u.x), s);
    s = fmaf(q[2], blo(u.y), s);  s = fmaf(q[3], bhi(u.y), s);
    s = fmaf(q[4], blo(u.z), s);  s = fmaf(q[5], bhi(u.z), s);
    s = fmaf(q[6], blo(u.w), s);  s = fmaf(q[7], bhi(u.w), s);
    return s;
}

__global__ __launch_bounds__(256, 4)
void attn_kernel(const unsigned short* __restrict__ QKV,
                 unsigned short* __restrict__ AO)
{
    const int t   = blockIdx.x * 256 + threadIdx.x;
    const int vox = t >> 5;                 // 32 threads per voxel
    const int ch  = (t & 31) * 8;           // head*32 + quarter*8
    const int d = (vox >> 8) & 15, h = (vox >> 4) & 15, w = vox & 15;

    float q[8];
    {
        uint4 u = *reinterpret_cast<const uint4*>(&QKV[(size_t)vox * 768 + ch]);
        q[0]=blo(u.x); q[1]=bhi(u.x); q[2]=blo(u.y); q[3]=bhi(u.y);
        q[4]=blo(u.z); q[5]=bhi(u.z); q[6]=blo(u.w); q[7]=bhi(u.w);
    }

    int nr[27];
    unsigned vm = 0;                        // validity bitmask
    #pragma unroll
    for (int kk = 0; kk < 27; ++kk) {
        const int di = kk / 9 - 1, hi2 = (kk / 3) % 3 - 1, wi = kk % 3 - 1;
        const int nd = d + di, nh = h + hi2, nw = w + wi;
        const bool valid = (kk != 13) && ((unsigned)nd < 16u) &&
                           ((unsigned)nh < 16u) && ((unsigned)nw < 16u);
        nr[kk] = valid ? ((vox & 4096) | (nd << 8) | (nh << 4) | nw) : vox;
        vm |= (unsigned)valid << kk;
    }

    float sc[27];
    #pragma unroll
    for (int g = 0; g < 3; ++g) {
        uint4 ku[9];
        #pragma unroll
        for (int j = 0; j < 9; ++j)
            ku[j] = *reinterpret_cast<const uint4*>(
                &QKV[(size_t)nr[g * 9 + j] * 768 + 256 + ch]);
        #pragma unroll
        for (int j = 0; j < 9; ++j) {
            float s = dot8(ku[j], q);
            s += __shfl_xor(s, 1);          // quad-perm DPP (VALU pipe)
            s += __shfl_xor(s, 2);
            sc[g * 9 + j] = ((vm >> (g * 9 + j)) & 1u) ? s : -INFINITY;
        }
    }

    float mx = sc[0];
    #pragma unroll
    for (int kk = 1; kk < 27; ++kk) mx = fmaxf(mx, sc[kk]);
    float z = 0.0f;
    #pragma unroll
    for (int kk = 0; kk < 27; ++kk) { float p = __expf(sc[kk] - mx); sc[kk] = p; z += p; }
    const float inv = 1.0f / z;

    float acc[8] = {};
    #pragma unroll
    for (int g = 0; g < 3; ++g) {
        uint4 vu[9];
        #pragma unroll
        for (int j = 0; j < 9; ++j)
            vu[j] = *reinterpret_cast<const uint4*>(
                &QKV[(size_t)nr[g * 9 + j] * 768 + 512 + ch]);
        #pragma unroll
        for (int j = 0; j < 9; ++j) {
            const float p = sc[g * 9 + j];
            const uint4 u = vu[j];
            acc[0] = fmaf(p, blo(u.x), acc[0]); acc[1] = fmaf(p, bhi(u.x), acc[1]);
            acc[2] = fmaf(p, blo(u.y), acc[2]); acc[3] = fmaf(p, bhi(u.y), acc[3]);
            acc[4] = fmaf(p, blo(u.z), acc[4]); acc[5] = fmaf(p, bhi(u.z), acc[5]);
            acc[6] = fmaf(p, blo(u.w), acc[6]); acc[7] = fmaf(p, bhi(u.w), acc[7]);
        }
    }

    uint4 o;
    o.x = (unsigned)f2b(acc[0] * inv) | ((unsigned)f2b(acc[1] * inv) << 16);
    o.y = (unsigned)f2b(acc[2] * inv) | ((unsigned)f2b(acc[3] * inv) << 16);
    o.z = (unsigned)f2b(acc[4] * inv) | ((unsigned)f2b(acc[5] * inv) << 16);
    o.w = (unsigned)f2b(acc[6] * inv) | ((unsigned)f2b(acc[7] * inv) << 16);
    *reinterpret_cast<uint4*>(&AO[(size_t)vox * C + ch]) = o;
}

// ---------------------------------------------------------------- launch
extern "C" void kernel_launch(void* const* d_in, const int* in_sizes, int n_in,
                              void* d_out, int out_size, void* d_ws, size_t ws_size,
                              hipStream_t stream)
{
    const float* x   = (const float*)d_in[0];
    const float* Wq  = (const float*)d_in[1];
    const float* bq  = (const float*)d_in[2];
    const float* Wk  = (const float*)d_in[3];
    const float* bk  = (const float*)d_in[4];
    const float* Wv  = (const float*)d_in[5];
    const float* bv  = (const float*)d_in[6];
    const float* Wo  = (const float*)d_in[7];
    const float* bo  = (const float*)d_in[8];
    const float* g1  = (const float*)d_in[9];
    const float* b1  = (const float*)d_in[10];
    const float* g2  = (const float*)d_in[11];
    const float* b2  = (const float*)d_in[12];
    const float* W1  = (const float*)d_in[13];
    const float* bf1 = (const float*)d_in[14];
    const float* W2  = (const float*)d_in[15];
    const float* bf2 = (const float*)d_in[16];

    char* ws = (char*)d_ws;
    size_t o = 0;
    unsigned short* WQT = (unsigned short*)(ws + o); o += (size_t)256 * 256 * 2;   // [768][256] with WKT/WVT
    unsigned short* WKT = (unsigned short*)(ws + o); o += (size_t)256 * 256 * 2;
    unsigned short* WVT = (unsigned short*)(ws + o); o += (size_t)256 * 256 * 2;
    unsigned short* WOT = (unsigned short*)(ws + o); o += (size_t)256 * 256 * 2;
    unsigned short* W1T = (unsigned short*)(ws + o); o += (size_t)256 * 1024 * 2;
    unsigned short* W2T = (unsigned short*)(ws + o); o += (size_t)1024 * 256 * 2;
    float*          bqkv= (float*)(ws + o);          o += (size_t)768 * 4;
    unsigned short* tn  = (unsigned short*)(ws + o); o += (size_t)NROW * C * 2;
    unsigned short* xb  = (unsigned short*)(ws + o); o += (size_t)NROW * C * 2;
    unsigned short* QKVb= (unsigned short*)(ws + o); o += (size_t)NROW * 768 * 2;
    unsigned short* AOb = (unsigned short*)(ws + o); o += (size_t)NROW * C * 2;
    float*          Tf  = (float*)(ws + o);          o += (size_t)NROW * C * 4;
    unsigned short* tn2 = (unsigned short*)(ws + o); o += (size_t)NROW * C * 2;
    unsigned short* Hb  = (unsigned short*)(ws + o); o += (size_t)NROW * F * 2;

    prep_ln_kernel<<<193 + NROW / 4, 256, 0, stream>>>(Wq, Wk, Wv, Wo, W1, W2, bq, bk, bv,
                                                       WQT, WKT, WVT, WOT, W1T, W2T, bqkv,
                                                       x, g1, b1, tn, xb);

    qkv_kernel<<<(NROW / 64) * 12, 256, 0, stream>>>(tn, xb, WQT, bqkv, QKVb);

    attn_kernel<<<NROW * 32 / 256, 256, 0, stream>>>(QKVb, AOb);

    gemm_kernel<256, 2, 4><<<(NROW / 64) * 4, 256, 0, stream>>>(AOb, WOT, bo, x, Tf, 256);

    ln_kernel<<<NROW / 4, 256, 0, stream>>>(Tf, g2, b2, tn2);

    gemm_kernel<256, 1, 16><<<(NROW / 64) * 16, 256, 0, stream>>>(tn2, W1T, bf1, nullptr, Hb, 1024);

    gemm_kernel<1024, 2, 4><<<(NROW / 64) * 4, 256, 0, stream>>>(Hb, W2T, bf2, Tf, (float*)d_out, 256);
}

// Round 12
// 74.968 us; speedup vs baseline: 1.0829x; 1.0642x over previous
//
#include <hip/hip_runtime.h>

typedef __bf16 bf16x8 __attribute__((ext_vector_type(8)));
typedef float f32x4 __attribute__((ext_vector_type(4)));

#define DEV static __device__ __forceinline__

DEV unsigned short f2b(float f){
    unsigned int u = __float_as_uint(f);
    u += 0x7fffu + ((u >> 16) & 1u);
    return (unsigned short)(u >> 16);
}
DEV float b2f(unsigned short h){ return __uint_as_float(((unsigned int)h) << 16); }
DEV float blo(unsigned int u){ return __uint_as_float(u << 16); }
DEV float bhi(unsigned int u){ return __uint_as_float(u & 0xffff0000u); }
DEV float gelu_f(float x){ return 0.5f * x * (1.0f + erff(x * 0.7071067811865476f)); }

// async global->LDS, 16B per lane, wave-uniform LDS base (HW adds lane*16).
DEV void gload16(const unsigned short* g, unsigned short* l){
    __builtin_amdgcn_global_load_lds(
        (const __attribute__((address_space(1))) void*)g,
        (__attribute__((address_space(3))) void*)l, 16, 0, 0);
}

// ---------------------------------------------------------------- constants
static constexpr int NROW = 8192;   // B*D*H*W = 2*16*16*16
static constexpr int C    = 256;
static constexpr int F    = 1024;
static constexpr float ATT_SCALE = 0.17677669529663688f;   // 1/sqrt(32)

// ---------------------------------------------------------------- prep + LN1
__global__ __launch_bounds__(256)
void prep_ln_kernel(const float* __restrict__ Wq, const float* __restrict__ Wk,
                    const float* __restrict__ Wv, const float* __restrict__ Wo,
                    const float* __restrict__ W1, const float* __restrict__ W2,
                    const float* __restrict__ bq, const float* __restrict__ bk,
                    const float* __restrict__ bv,
                    unsigned short* __restrict__ WQT, unsigned short* __restrict__ WKT,
                    unsigned short* __restrict__ WVT, unsigned short* __restrict__ WOT,
                    unsigned short* __restrict__ W1T, unsigned short* __restrict__ W2T,
                    float* __restrict__ bqkv,
                    const float* __restrict__ x, const float* __restrict__ g1,
                    const float* __restrict__ b1,
                    unsigned short* __restrict__ tn, unsigned short* __restrict__ xb)
{
    const int tid = threadIdx.x;
    if (blockIdx.x < 192) {
        __shared__ unsigned short T[64][66];
        const int t = blockIdx.x;
        const float* src; unsigned short* dst;
        int ldw, ldt, r0, c0; float sc = 1.0f;
        if (t < 64) {                       // 4 square 256x256 mats, 16 tiles each
            const int m = t >> 4, sub = t & 15;
            src = (m == 0) ? Wq : (m == 1) ? Wk : (m == 2) ? Wv : Wo;
            dst = (m == 0) ? WQT : (m == 1) ? WKT : (m == 2) ? WVT : WOT;
            if (m == 0) sc = ATT_SCALE;
            ldw = 256; ldt = 256;
            r0 = (sub >> 2) * 64; c0 = (sub & 3) * 64;
        } else if (t < 128) {               // W1: 256x1024 -> W1T [1024][256]
            const int sub = t - 64;
            src = W1; dst = W1T; ldw = 1024; ldt = 256;
            r0 = (sub >> 4) * 64; c0 = (sub & 15) * 64;
        } else {                            // W2: 1024x256 -> W2T [256][1024]
            const int sub = t - 128;
            src = W2; dst = W2T; ldw = 256; ldt = 1024;
            r0 = (sub >> 2) * 64; c0 = (sub & 3) * 64;
        }
        #pragma unroll
        for (int i = 0; i < 16; ++i) {
            const int rl = i * 4 + (tid >> 6), cl = tid & 63;
            T[rl][cl] = f2b(src[(size_t)(r0 + rl) * ldw + c0 + cl] * sc);
        }
        __syncthreads();
        #pragma unroll
        for (int j = 0; j < 16; ++j) {
            const int cl = j * 4 + (tid >> 6), rl = tid & 63;
            dst[(size_t)(c0 + cl) * ldt + r0 + rl] = T[rl][cl];
        }
    } else if (blockIdx.x == 192) {
        #pragma unroll
        for (int i = 0; i < 3; ++i) {
            const int v = i * 256 + tid;
            bqkv[v] = (v < 256) ? bq[v] * ATT_SCALE
                    : (v < 512) ? bk[v - 256] : bv[v - 512];
        }
    } else {
        const int row  = (blockIdx.x - 193) * 4 + (tid >> 6);
        const int lane = tid & 63;
        float4 v = ((const float4*)(x + (size_t)row * C))[lane];
        float s = v.x + v.y + v.z + v.w;
        #pragma unroll
        for (int m = 32; m >= 1; m >>= 1) s += __shfl_xor(s, m);
        const float mean = s * (1.0f / 256.0f);
        const float d0 = v.x - mean, d1 = v.y - mean, d2 = v.z - mean, d3 = v.w - mean;
        float s2 = d0 * d0 + d1 * d1 + d2 * d2 + d3 * d3;
        #pragma unroll
        for (int m = 32; m >= 1; m >>= 1) s2 += __shfl_xor(s2, m);
        const float rstd = rsqrtf(s2 * (1.0f / 256.0f) + 1e-5f);
        float4 gg = ((const float4*)g1)[lane];
        float4 bb = ((const float4*)b1)[lane];
        ushort4 o = { f2b(d0 * rstd * gg.x + bb.x), f2b(d1 * rstd * gg.y + bb.y),
                      f2b(d2 * rstd * gg.z + bb.z), f2b(d3 * rstd * gg.w + bb.w) };
        ((ushort4*)(tn + (size_t)row * C))[lane] = o;
        ushort4 xo = { f2b(v.x), f2b(v.y), f2b(v.z), f2b(v.w) };
        ((ushort4*)(xb + (size_t)row * C))[lane] = xo;
    }
}

// ---------------------------------------------------------------- LN2
__global__ __launch_bounds__(256)
void ln_kernel(const float* __restrict__ X, const float* __restrict__ g,
               const float* __restrict__ bta, unsigned short* __restrict__ OUT)
{
    const int row  = blockIdx.x * 4 + (threadIdx.x >> 6);
    const int lane = threadIdx.x & 63;
    float4 v = ((const float4*)(X + (size_t)row * C))[lane];
    float s = v.x + v.y + v.z + v.w;
    #pragma unroll
    for (int m = 32; m >= 1; m >>= 1) s += __shfl_xor(s, m);
    const float mean = s * (1.0f / 256.0f);
    const float d0 = v.x - mean, d1 = v.y - mean, d2 = v.z - mean, d3 = v.w - mean;
    float s2 = d0 * d0 + d1 * d1 + d2 * d2 + d3 * d3;
    #pragma unroll
    for (int m = 32; m >= 1; m >>= 1) s2 += __shfl_xor(s2, m);
    const float rstd = rsqrtf(s2 * (1.0f / 256.0f) + 1e-5f);
    float4 gg = ((const float4*)g)[lane];
    float4 bb = ((const float4*)bta)[lane];
    ushort4 o = { f2b(d0 * rstd * gg.x + bb.x), f2b(d1 * rstd * gg.y + bb.y),
                  f2b(d2 * rstd * gg.z + bb.z), f2b(d3 * rstd * gg.w + bb.w) };
    ((ushort4*)(OUT + (size_t)row * C))[lane] = o;
}

// ---------------------------------------------------------------- 64x64 GEMM
// (kept for N=256 GEMMs: Wo, W2 — 512 blocks = 2/CU beats 256 blocks of 64x128)
template<int K, int MODE>
DEV void gemm_body(const unsigned short* __restrict__ A, int m0,
                   const unsigned short* __restrict__ BTt,
                   const float* __restrict__ biast,
                   const float* __restrict__ res, void* __restrict__ outp,
                   int ldo, int ocol0,
                   unsigned short (&As)[2][4096], unsigned short (&Bs)[2][4096])
{
    constexpr int BK = 64, NKT = K / BK;
    const int tid  = threadIdx.x;
    const int lane = tid & 63, wid = tid >> 6;
    const int srow = tid >> 3;                    // 0..31
    const int schk = (tid & 7) ^ (srow & 7);      // inverse-swizzled src chunk

    const unsigned short* Ag = A   + (size_t)(m0 + srow) * K + schk * 8;
    const unsigned short* Bg = BTt + (size_t)srow        * K + schk * 8;

    const int wbase = __builtin_amdgcn_readfirstlane(wid) * 512;

    gload16(Ag,          &As[0][wbase]);
    gload16(Ag + 32 * K, &As[0][wbase + 2048]);
    gload16(Bg,          &Bs[0][wbase]);
    gload16(Bg + 32 * K, &Bs[0][wbase + 2048]);
    __syncthreads();

    f32x4 acc[4] = {};
    const int lr = lane & 15, lk = lane >> 4;
    const int sw = lr & 7;

    for (int kt = 0; kt < NKT; ++kt) {
        if (kt + 1 < NKT) {
            const int nb = (kt + 1) & 1;
            gload16(Ag + (kt + 1) * BK,          &As[nb][wbase]);
            gload16(Ag + 32 * K + (kt + 1) * BK, &As[nb][wbase + 2048]);
            gload16(Bg + (kt + 1) * BK,          &Bs[nb][wbase]);
            gload16(Bg + 32 * K + (kt + 1) * BK, &Bs[nb][wbase + 2048]);
        }
        const unsigned short* as = As[kt & 1];
        const unsigned short* bs = Bs[kt & 1];
        #pragma unroll
        for (int s = 0; s < 2; ++s) {
            const int c16 = (s * 4 + lk) ^ sw;
            bf16x8 bfr = *reinterpret_cast<const bf16x8*>(&bs[(wid * 16 + lr) * 64 + c16 * 8]);
            #pragma unroll
            for (int m = 0; m < 4; ++m) {
                bf16x8 afr = *reinterpret_cast<const bf16x8*>(&as[(m * 16 + lr) * 64 + c16 * 8]);
                acc[m] = __builtin_amdgcn_mfma_f32_16x16x32_bf16(afr, bfr, acc[m], 0, 0, 0);
            }
        }
        if (kt + 1 < NKT) __syncthreads();
    }

    const int col  = ocol0 + wid * 16 + lr;
    const float bcol = biast[wid * 16 + lr];
    #pragma unroll
    for (int m = 0; m < 4; ++m) {
        #pragma unroll
        for (int r = 0; r < 4; ++r) {
            const int row = m0 + m * 16 + lk * 4 + r;
            float v = acc[m][r] + bcol;
            if (MODE == 0) {
                ((unsigned short*)outp)[(size_t)row * ldo + col] = f2b(v);
            } else if (MODE == 1) {
                ((unsigned short*)outp)[(size_t)row * ldo + col] = f2b(gelu_f(v));
            } else {
                v += res[(size_t)row * ldo + col];
                ((float*)outp)[(size_t)row * ldo + col] = v;
            }
        }
    }
}

// ---------------------------------------------------------------- 64x128 GEMM
// M=64, N=128, BK=64, 4 waves; wave owns 64 rows x 32 cols (acc[4][2], 32 VGPR).
// Same A-staging as the proven 64x64 body (2 gloads); B doubled to 128 rows
// (4 gloads). MFMA:ds_read = 16:12 vs 8:10. LDS 48KB -> 3 blocks/CU.
template<int K, int MODE>
DEV void gemm_bodyN128(const unsigned short* __restrict__ A, int m0,
                       const unsigned short* __restrict__ BTt,  // BT + n0*K
                       const float* __restrict__ biast,
                       const float* __restrict__ res, void* __restrict__ outp,
                       int ldo, int ocol0,
                       unsigned short (&As)[2][4096], unsigned short (&Bs)[2][8192])
{
    constexpr int BK = 64, NKT = K / BK;
    const int tid  = threadIdx.x;
    const int lane = tid & 63, wid = tid >> 6;
    const int srow = tid >> 3;                    // 0..31
    const int schk = (tid & 7) ^ (srow & 7);

    const unsigned short* Ag = A   + (size_t)(m0 + srow) * K + schk * 8;
    const unsigned short* Bg = BTt + (size_t)srow        * K + schk * 8;

    const int wbase = __builtin_amdgcn_readfirstlane(wid) * 512;

    gload16(Ag,          &As[0][wbase]);
    gload16(Ag + 32 * K, &As[0][wbase + 2048]);
    #pragma unroll
    for (int i = 0; i < 4; ++i)
        gload16(Bg + (size_t)(32 * i) * K, &Bs[0][i * 2048 + wbase]);
    __syncthreads();

    f32x4 acc[4][2] = {};
    const int lr = lane & 15, lk = lane >> 4;
    const int sw = lr & 7;
    const int brow = wid * 32;                    // wave's B-row (output col) base

    for (int kt = 0; kt < NKT; ++kt) {
        if (kt + 1 < NKT) {
            const int nb = (kt + 1) & 1;
            gload16(Ag + (kt + 1) * BK,          &As[nb][wbase]);
            gload16(Ag + 32 * K + (kt + 1) * BK, &As[nb][wbase + 2048]);
            #pragma unroll
            for (int i = 0; i < 4; ++i)
                gload16(Bg + (size_t)(32 * i) * K + (kt + 1) * BK, &Bs[nb][i * 2048 + wbase]);
        }
        const unsigned short* as = As[kt & 1];
        const unsigned short* bs = Bs[kt & 1];
        #pragma unroll
        for (int ks = 0; ks < 2; ++ks) {
            const int c16 = (ks * 4 + lk) ^ sw;
            bf16x8 af[4], bf[2];
            #pragma unroll
            for (int m = 0; m < 4; ++m)
                af[m] = *reinterpret_cast<const bf16x8*>(&as[(m * 16 + lr) * 64 + c16 * 8]);
            #pragma unroll
            for (int n = 0; n < 2; ++n)
                bf[n] = *reinterpret_cast<const bf16x8*>(&bs[(brow + n * 16 + lr) * 64 + c16 * 8]);
            #pragma unroll
            for (int m = 0; m < 4; ++m)
                #pragma unroll
                for (int n = 0; n < 2; ++n)
                    acc[m][n] = __builtin_amdgcn_mfma_f32_16x16x32_bf16(af[m], bf[n], acc[m][n], 0, 0, 0);
        }
        if (kt + 1 < NKT) __syncthreads();
    }

    #pragma unroll
    for (int n = 0; n < 2; ++n) {
        const int cl  = brow + n * 16 + lr;
        const int col = ocol0 + cl;
        const float bcol = biast[cl];
        #pragma unroll
        for (int m = 0; m < 4; ++m) {
            #pragma unroll
            for (int r = 0; r < 4; ++r) {
                const int row = m0 + m * 16 + lk * 4 + r;
                float v = acc[m][n][r] + bcol;
                if (MODE == 0) {
                    ((unsigned short*)outp)[(size_t)row * ldo + col] = f2b(v);
                } else if (MODE == 1) {
                    ((unsigned short*)outp)[(size_t)row * ldo + col] = f2b(gelu_f(v));
                } else {
                    v += res[(size_t)row * ldo + col];
                    ((float*)outp)[(size_t)row * ldo + col] = v;
                }
            }
        }
    }
}

// XCD-swizzled 1D-grid tile maps, column-fastest (T1). Requires nwg % 8 == 0.
template<int NC, int TS>
DEV void tile_map(int& m0, int& n0){
    const int nwg = gridDim.x;
    const int lin = blockIdx.x;
    const int tile = (lin & 7) * (nwg >> 3) + (lin >> 3);
    m0 = (tile / NC) * TS;
    n0 = (tile % NC) * TS;
}
template<int NC, int TSM, int TSN>
DEV void tile_map2(int& m0, int& n0){
    const int nwg = gridDim.x;
    const int lin = blockIdx.x;
    const int tile = (lin & 7) * (nwg >> 3) + (lin >> 3);
    m0 = (tile / NC) * TSM;
    n0 = (tile % NC) * TSN;
}

// Fused Q/K/V GEMM at 64x128: N=768, A = tn for Q cols (n0<256), xb for K/V.
__global__ __launch_bounds__(256, 3)
void qkv_kernel(const unsigned short* __restrict__ tn,
                const unsigned short* __restrict__ xb,
                const unsigned short* __restrict__ WT,    // [768][256]
                const float* __restrict__ bqkv,           // [768]
                unsigned short* __restrict__ QKV)         // [8192][768]
{
    __shared__ unsigned short As[2][4096], Bs[2][8192];
    int m0, n0; tile_map2<6, 64, 128>(m0, n0);
    const unsigned short* A = (n0 < 256) ? tn : xb;
    gemm_bodyN128<256, 0>(A, m0, WT + (size_t)n0 * 256,
                          bqkv + n0, nullptr, QKV, 768, n0, As, Bs);
}

// W1 GEMM at 64x128 with GELU epilogue.
__global__ __launch_bounds__(256, 3)
void w1_kernel(const unsigned short* __restrict__ tn2,
               const unsigned short* __restrict__ W1T,    // [1024][256]
               const float* __restrict__ bf1,
               unsigned short* __restrict__ Hb)           // [8192][1024]
{
    __shared__ unsigned short As[2][4096], Bs[2][8192];
    int m0, n0; tile_map2<8, 64, 128>(m0, n0);
    gemm_bodyN128<256, 1>(tn2, m0, W1T + (size_t)n0 * 256,
                          bf1 + n0, nullptr, Hb, 1024, n0, As, Bs);
}

template<int K, int MODE, int NC>
__global__ __launch_bounds__(256)
void gemm_kernel(const unsigned short* __restrict__ A,
                 const unsigned short* __restrict__ BT,
                 const float* __restrict__ bias,
                 const float* __restrict__ res,
                 void* __restrict__ outp, int ldo)
{
    __shared__ unsigned short As[2][4096], Bs[2][4096];
    int m0, n0; tile_map<NC, 64>(m0, n0);
    gemm_body<K, MODE>(A, m0, BT + (size_t)n0 * K,
                       bias + n0, res, outp, ldo, n0, As, Bs);
}

// ---------------------------------------------------------------- attention
// Thread = (voxel, head, quarter), 16 waves/CU. ONLINE SOFTMAX: K and V of
// each 9-group processed in one pass with running (m, z, acc) rescale —
// removes the sc[27]/nr[27] arrays (~36 VGPR) and interleaves K/V gathers.
// Invalid neighbors: s = -inf; m_run starts at -1e30 (finite) so every exp
// argument is finite or -inf -> p = 0 exactly. No branches.
// QKV layout: [NROW][768] bf16: Q (pre-scaled) 0..255, K 256..511, V 512..767.
DEV float dot8(uint4 u, const float* q){
    float s;
    s = q[0] * blo(u.x);          s = fmaf(q[1], bhi(u.x), s);
    s = fmaf(q[2], blo(u.y), s);  s = fmaf(q[3], bhi(u.y), s);
    s = fmaf(q[4], blo(u.z), s);  s = fmaf(q[5], bhi(u.z), s);
    s = fmaf(q[6], blo(u.w), s);  s = fmaf(q[7], bhi(u.w), s);
    return s;
}

__global__ __launch_bounds__(256, 4)
void attn_kernel(const unsigned short* __restrict__ QKV,
                 unsigned short* __restrict__ AO)
{
    const int t   = blockIdx.x * 256 + threadIdx.x;
    const int vox = t >> 5;                 // 32 threads per voxel
    const int ch  = (t & 31) * 8;           // head*32 + quarter*8
    const int d = (vox >> 8) & 15, h = (vox >> 4) & 15, w = vox & 15;

    float q[8];
    {
        uint4 u = *reinterpret_cast<const uint4*>(&QKV[(size_t)vox * 768 + ch]);
        q[0]=blo(u.x); q[1]=bhi(u.x); q[2]=blo(u.y); q[3]=bhi(u.y);
        q[4]=blo(u.z); q[5]=bhi(u.z); q[6]=blo(u.w); q[7]=bhi(u.w);
    }

    float mrun = -1e30f, z = 0.0f;
    float acc[8] = {};

    #pragma unroll
    for (int g = 0; g < 3; ++g) {
        const int di = g - 1;
        const int nd = d + di;
        int r9[9];
        unsigned vm = 0;
        #pragma unroll
        for (int j = 0; j < 9; ++j) {
            const int hi2 = j / 3 - 1, wi = j % 3 - 1;
            const int nh = h + hi2, nw = w + wi;
            const bool valid = !(di == 0 && hi2 == 0 && wi == 0) &&
                               ((unsigned)nd < 16u) && ((unsigned)nh < 16u) &&
                               ((unsigned)nw < 16u);
            r9[j] = valid ? ((vox & 4096) | (nd << 8) | (nh << 4) | nw) : vox;
            vm |= (unsigned)valid << j;
        }

        uint4 ku[9];
        #pragma unroll
        for (int j = 0; j < 9; ++j)
            ku[j] = *reinterpret_cast<const uint4*>(
                &QKV[(size_t)r9[j] * 768 + 256 + ch]);

        float s9[9];
        #pragma unroll
        for (int j = 0; j < 9; ++j) {
            float s = dot8(ku[j], q);
            s += __shfl_xor(s, 1);          // quad-perm DPP (VALU pipe)
            s += __shfl_xor(s, 2);
            s9[j] = ((vm >> j) & 1u) ? s : -INFINITY;
        }

        float gm = s9[0];
        #pragma unroll
        for (int j = 1; j < 9; ++j) gm = fmaxf(gm, s9[j]);
        const float nm = fmaxf(mrun, gm);   // finite always (mrun >= -1e30)
        const float rs = __expf(mrun - nm);
        mrun = nm;
        z *= rs;
        #pragma unroll
        for (int i = 0; i < 8; ++i) acc[i] *= rs;

        uint4 vu[9];
        #pragma unroll
        for (int j = 0; j < 9; ++j)
            vu[j] = *reinterpret_cast<const uint4*>(
                &QKV[(size_t)r9[j] * 768 + 512 + ch]);

        #pragma unroll
        for (int j = 0; j < 9; ++j) {
            const float p = __expf(s9[j] - nm);   // -inf -> exactly 0
            z += p;
            const uint4 u = vu[j];
            acc[0] = fmaf(p, blo(u.x), acc[0]); acc[1] = fmaf(p, bhi(u.x), acc[1]);
            acc[2] = fmaf(p, blo(u.y), acc[2]); acc[3] = fmaf(p, bhi(u.y), acc[3]);
            acc[4] = fmaf(p, blo(u.z), acc[4]); acc[5] = fmaf(p, bhi(u.z), acc[5]);
            acc[6] = fmaf(p, blo(u.w), acc[6]); acc[7] = fmaf(p, bhi(u.w), acc[7]);
        }
    }

    const float inv = 1.0f / z;
    uint4 o;
    o.x = (unsigned)f2b(acc[0] * inv) | ((unsigned)f2b(acc[1] * inv) << 16);
    o.y = (unsigned)f2b(acc[2] * inv) | ((unsigned)f2b(acc[3] * inv) << 16);
    o.z = (unsigned)f2b(acc[4] * inv) | ((unsigned)f2b(acc[5] * inv) << 16);
    o.w = (unsigned)f2b(acc[6] * inv) | ((unsigned)f2b(acc[7] * inv) << 16);
    *reinterpret_cast<uint4*>(&AO[(size_t)vox * C + ch]) = o;
}

// ---------------------------------------------------------------- launch
extern "C" void kernel_launch(void* const* d_in, const int* in_sizes, int n_in,
                              void* d_out, int out_size, void* d_ws, size_t ws_size,
                              hipStream_t stream)
{
    const float* x   = (const float*)d_in[0];
    const float* Wq  = (const float*)d_in[1];
    const float* bq  = (const float*)d_in[2];
    const float* Wk  = (const float*)d_in[3];
    const float* bk  = (const float*)d_in[4];
    const float* Wv  = (const float*)d_in[5];
    const float* bv  = (const float*)d_in[6];
    const float* Wo  = (const float*)d_in[7];
    const float* bo  = (const float*)d_in[8];
    const float* g1  = (const float*)d_in[9];
    const float* b1  = (const float*)d_in[10];
    const float* g2  = (const float*)d_in[11];
    const float* b2  = (const float*)d_in[12];
    const float* W1  = (const float*)d_in[13];
    const float* bf1 = (const float*)d_in[14];
    const float* W2  = (const float*)d_in[15];
    const float* bf2 = (const float*)d_in[16];

    char* ws = (char*)d_ws;
    size_t o = 0;
    unsigned short* WQT = (unsigned short*)(ws + o); o += (size_t)256 * 256 * 2;   // [768][256] with WKT/WVT
    unsigned short* WKT = (unsigned short*)(ws + o); o += (size_t)256 * 256 * 2;
    unsigned short* WVT = (unsigned short*)(ws + o); o += (size_t)256 * 256 * 2;
    unsigned short* WOT = (unsigned short*)(ws + o); o += (size_t)256 * 256 * 2;
    unsigned short* W1T = (unsigned short*)(ws + o); o += (size_t)256 * 1024 * 2;
    unsigned short* W2T = (unsigned short*)(ws + o); o += (size_t)1024 * 256 * 2;
    float*          bqkv= (float*)(ws + o);          o += (size_t)768 * 4;
    unsigned short* tn  = (unsigned short*)(ws + o); o += (size_t)NROW * C * 2;
    unsigned short* xb  = (unsigned short*)(ws + o); o += (size_t)NROW * C * 2;
    unsigned short* QKVb= (unsigned short*)(ws + o); o += (size_t)NROW * 768 * 2;
    unsigned short* AOb = (unsigned short*)(ws + o); o += (size_t)NROW * C * 2;
    float*          Tf  = (float*)(ws + o);          o += (size_t)NROW * C * 4;
    unsigned short* tn2 = (unsigned short*)(ws + o); o += (size_t)NROW * C * 2;
    unsigned short* Hb  = (unsigned short*)(ws + o); o += (size_t)NROW * F * 2;

    prep_ln_kernel<<<193 + NROW / 4, 256, 0, stream>>>(Wq, Wk, Wv, Wo, W1, W2, bq, bk, bv,
                                                       WQT, WKT, WVT, WOT, W1T, W2T, bqkv,
                                                       x, g1, b1, tn, xb);

    qkv_kernel<<<(NROW / 64) * 6, 256, 0, stream>>>(tn, xb, WQT, bqkv, QKVb);

    attn_kernel<<<NROW * 32 / 256, 256, 0, stream>>>(QKVb, AOb);

    gemm_kernel<256, 2, 4><<<(NROW / 64) * 4, 256, 0, stream>>>(AOb, WOT, bo, x, Tf, 256);

    ln_kernel<<<NROW / 4, 256, 0, stream>>>(Tf, g2, b2, tn2);

    w1_kernel<<<(NROW / 64) * 8, 256, 0, stream>>>(tn2, W1T, bf1, Hb);

    gemm_kernel<1024, 2, 4><<<(NROW / 64) * 4, 256, 0, stream>>>(Hb, W2T, bf2, Tf, (float*)d_out, 256);
}

// Round 13
// 74.526 us; speedup vs baseline: 1.0893x; 1.0059x over previous
//
#include <hip/hip_runtime.h>

typedef __bf16 bf16x8 __attribute__((ext_vector_type(8)));
typedef float f32x4 __attribute__((ext_vector_type(4)));

#define DEV static __device__ __forceinline__

DEV unsigned short f2b(float f){
    unsigned int u = __float_as_uint(f);
    u += 0x7fffu + ((u >> 16) & 1u);
    return (unsigned short)(u >> 16);
}
DEV float b2f(unsigned short h){ return __uint_as_float(((unsigned int)h) << 16); }
DEV float blo(unsigned int u){ return __uint_as_float(u << 16); }
DEV float bhi(unsigned int u){ return __uint_as_float(u & 0xffff0000u); }
DEV float gelu_f(float x){ return 0.5f * x * (1.0f + erff(x * 0.7071067811865476f)); }

// async global->LDS, 16B per lane, wave-uniform LDS base (HW adds lane*16).
DEV void gload16(const unsigned short* g, unsigned short* l){
    __builtin_amdgcn_global_load_lds(
        (const __attribute__((address_space(1))) void*)g,
        (__attribute__((address_space(3))) void*)l, 16, 0, 0);
}

// ---------------------------------------------------------------- constants
static constexpr int NROW = 8192;   // B*D*H*W = 2*16*16*16
static constexpr int C    = 256;
static constexpr int F    = 1024;
static constexpr float ATT_SCALE = 0.17677669529663688f;   // 1/sqrt(32)

// ---------------------------------------------------------------- prep + LN1
__global__ __launch_bounds__(256)
void prep_ln_kernel(const float* __restrict__ Wq, const float* __restrict__ Wk,
                    const float* __restrict__ Wv, const float* __restrict__ Wo,
                    const float* __restrict__ W1, const float* __restrict__ W2,
                    const float* __restrict__ bq, const float* __restrict__ bk,
                    const float* __restrict__ bv,
                    unsigned short* __restrict__ WQT, unsigned short* __restrict__ WKT,
                    unsigned short* __restrict__ WVT, unsigned short* __restrict__ WOT,
                    unsigned short* __restrict__ W1T, unsigned short* __restrict__ W2T,
                    float* __restrict__ bqkv,
                    const float* __restrict__ x, const float* __restrict__ g1,
                    const float* __restrict__ b1,
                    unsigned short* __restrict__ tn, unsigned short* __restrict__ xb)
{
    const int tid = threadIdx.x;
    if (blockIdx.x < 192) {
        __shared__ unsigned short T[64][66];
        const int t = blockIdx.x;
        const float* src; unsigned short* dst;
        int ldw, ldt, r0, c0; float sc = 1.0f;
        if (t < 64) {                       // 4 square 256x256 mats, 16 tiles each
            const int m = t >> 4, sub = t & 15;
            src = (m == 0) ? Wq : (m == 1) ? Wk : (m == 2) ? Wv : Wo;
            dst = (m == 0) ? WQT : (m == 1) ? WKT : (m == 2) ? WVT : WOT;
            if (m == 0) sc = ATT_SCALE;
            ldw = 256; ldt = 256;
            r0 = (sub >> 2) * 64; c0 = (sub & 3) * 64;
        } else if (t < 128) {               // W1: 256x1024 -> W1T [1024][256]
            const int sub = t - 64;
            src = W1; dst = W1T; ldw = 1024; ldt = 256;
            r0 = (sub >> 4) * 64; c0 = (sub & 15) * 64;
        } else {                            // W2: 1024x256 -> W2T [256][1024]
            const int sub = t - 128;
            src = W2; dst = W2T; ldw = 256; ldt = 1024;
            r0 = (sub >> 2) * 64; c0 = (sub & 3) * 64;
        }
        #pragma unroll
        for (int i = 0; i < 16; ++i) {
            const int rl = i * 4 + (tid >> 6), cl = tid & 63;
            T[rl][cl] = f2b(src[(size_t)(r0 + rl) * ldw + c0 + cl] * sc);
        }
        __syncthreads();
        #pragma unroll
        for (int j = 0; j < 16; ++j) {
            const int cl = j * 4 + (tid >> 6), rl = tid & 63;
            dst[(size_t)(c0 + cl) * ldt + r0 + rl] = T[rl][cl];
        }
    } else if (blockIdx.x == 192) {
        #pragma unroll
        for (int i = 0; i < 3; ++i) {
            const int v = i * 256 + tid;
            bqkv[v] = (v < 256) ? bq[v] * ATT_SCALE
                    : (v < 512) ? bk[v - 256] : bv[v - 512];
        }
    } else {
        const int row  = (blockIdx.x - 193) * 4 + (tid >> 6);
        const int lane = tid & 63;
        float4 v = ((const float4*)(x + (size_t)row * C))[lane];
        float s = v.x + v.y + v.z + v.w;
        #pragma unroll
        for (int m = 32; m >= 1; m >>= 1) s += __shfl_xor(s, m);
        const float mean = s * (1.0f / 256.0f);
        const float d0 = v.x - mean, d1 = v.y - mean, d2 = v.z - mean, d3 = v.w - mean;
        float s2 = d0 * d0 + d1 * d1 + d2 * d2 + d3 * d3;
        #pragma unroll
        for (int m = 32; m >= 1; m >>= 1) s2 += __shfl_xor(s2, m);
        const float rstd = rsqrtf(s2 * (1.0f / 256.0f) + 1e-5f);
        float4 gg = ((const float4*)g1)[lane];
        float4 bb = ((const float4*)b1)[lane];
        ushort4 o = { f2b(d0 * rstd * gg.x + bb.x), f2b(d1 * rstd * gg.y + bb.y),
                      f2b(d2 * rstd * gg.z + bb.z), f2b(d3 * rstd * gg.w + bb.w) };
        ((ushort4*)(tn + (size_t)row * C))[lane] = o;
        ushort4 xo = { f2b(v.x), f2b(v.y), f2b(v.z), f2b(v.w) };
        ((ushort4*)(xb + (size_t)row * C))[lane] = xo;
    }
}

// ---------------------------------------------------------------- 64x64 GEMM
// (kept for W2: K=1024, N=256)
template<int K, int MODE>
DEV void gemm_body(const unsigned short* __restrict__ A, int m0,
                   const unsigned short* __restrict__ BTt,
                   const float* __restrict__ biast,
                   const float* __restrict__ res, void* __restrict__ outp,
                   int ldo, int ocol0,
                   unsigned short (&As)[2][4096], unsigned short (&Bs)[2][4096])
{
    constexpr int BK = 64, NKT = K / BK;
    const int tid  = threadIdx.x;
    const int lane = tid & 63, wid = tid >> 6;
    const int srow = tid >> 3;                    // 0..31
    const int schk = (tid & 7) ^ (srow & 7);      // inverse-swizzled src chunk

    const unsigned short* Ag = A   + (size_t)(m0 + srow) * K + schk * 8;
    const unsigned short* Bg = BTt + (size_t)srow        * K + schk * 8;

    const int wbase = __builtin_amdgcn_readfirstlane(wid) * 512;

    gload16(Ag,          &As[0][wbase]);
    gload16(Ag + 32 * K, &As[0][wbase + 2048]);
    gload16(Bg,          &Bs[0][wbase]);
    gload16(Bg + 32 * K, &Bs[0][wbase + 2048]);
    __syncthreads();

    f32x4 acc[4] = {};
    const int lr = lane & 15, lk = lane >> 4;
    const int sw = lr & 7;

    for (int kt = 0; kt < NKT; ++kt) {
        if (kt + 1 < NKT) {
            const int nb = (kt + 1) & 1;
            gload16(Ag + (kt + 1) * BK,          &As[nb][wbase]);
            gload16(Ag + 32 * K + (kt + 1) * BK, &As[nb][wbase + 2048]);
            gload16(Bg + (kt + 1) * BK,          &Bs[nb][wbase]);
            gload16(Bg + 32 * K + (kt + 1) * BK, &Bs[nb][wbase + 2048]);
        }
        const unsigned short* as = As[kt & 1];
        const unsigned short* bs = Bs[kt & 1];
        #pragma unroll
        for (int s = 0; s < 2; ++s) {
            const int c16 = (s * 4 + lk) ^ sw;
            bf16x8 bfr = *reinterpret_cast<const bf16x8*>(&bs[(wid * 16 + lr) * 64 + c16 * 8]);
            #pragma unroll
            for (int m = 0; m < 4; ++m) {
                bf16x8 afr = *reinterpret_cast<const bf16x8*>(&as[(m * 16 + lr) * 64 + c16 * 8]);
                acc[m] = __builtin_amdgcn_mfma_f32_16x16x32_bf16(afr, bfr, acc[m], 0, 0, 0);
            }
        }
        if (kt + 1 < NKT) __syncthreads();
    }

    const int col  = ocol0 + wid * 16 + lr;
    const float bcol = biast[wid * 16 + lr];
    #pragma unroll
    for (int m = 0; m < 4; ++m) {
        #pragma unroll
        for (int r = 0; r < 4; ++r) {
            const int row = m0 + m * 16 + lk * 4 + r;
            float v = acc[m][r] + bcol;
            if (MODE == 0) {
                ((unsigned short*)outp)[(size_t)row * ldo + col] = f2b(v);
            } else if (MODE == 1) {
                ((unsigned short*)outp)[(size_t)row * ldo + col] = f2b(gelu_f(v));
            } else {
                v += res[(size_t)row * ldo + col];
                ((float*)outp)[(size_t)row * ldo + col] = v;
            }
        }
    }
}

// ---------------------------------------------------------------- 64x128 GEMM
template<int K, int MODE>
DEV void gemm_bodyN128(const unsigned short* __restrict__ A, int m0,
                       const unsigned short* __restrict__ BTt,  // BT + n0*K
                       const float* __restrict__ biast,
                       const float* __restrict__ res, void* __restrict__ outp,
                       int ldo, int ocol0,
                       unsigned short (&As)[2][4096], unsigned short (&Bs)[2][8192])
{
    constexpr int BK = 64, NKT = K / BK;
    const int tid  = threadIdx.x;
    const int lane = tid & 63, wid = tid >> 6;
    const int srow = tid >> 3;                    // 0..31
    const int schk = (tid & 7) ^ (srow & 7);

    const unsigned short* Ag = A   + (size_t)(m0 + srow) * K + schk * 8;
    const unsigned short* Bg = BTt + (size_t)srow        * K + schk * 8;

    const int wbase = __builtin_amdgcn_readfirstlane(wid) * 512;

    gload16(Ag,          &As[0][wbase]);
    gload16(Ag + 32 * K, &As[0][wbase + 2048]);
    #pragma unroll
    for (int i = 0; i < 4; ++i)
        gload16(Bg + (size_t)(32 * i) * K, &Bs[0][i * 2048 + wbase]);
    __syncthreads();

    f32x4 acc[4][2] = {};
    const int lr = lane & 15, lk = lane >> 4;
    const int sw = lr & 7;
    const int brow = wid * 32;                    // wave's B-row (output col) base

    for (int kt = 0; kt < NKT; ++kt) {
        if (kt + 1 < NKT) {
            const int nb = (kt + 1) & 1;
            gload16(Ag + (kt + 1) * BK,          &As[nb][wbase]);
            gload16(Ag + 32 * K + (kt + 1) * BK, &As[nb][wbase + 2048]);
            #pragma unroll
            for (int i = 0; i < 4; ++i)
                gload16(Bg + (size_t)(32 * i) * K + (kt + 1) * BK, &Bs[nb][i * 2048 + wbase]);
        }
        const unsigned short* as = As[kt & 1];
        const unsigned short* bs = Bs[kt & 1];
        #pragma unroll
        for (int ks = 0; ks < 2; ++ks) {
            const int c16 = (ks * 4 + lk) ^ sw;
            bf16x8 af[4], bf[2];
            #pragma unroll
            for (int m = 0; m < 4; ++m)
                af[m] = *reinterpret_cast<const bf16x8*>(&as[(m * 16 + lr) * 64 + c16 * 8]);
            #pragma unroll
            for (int n = 0; n < 2; ++n)
                bf[n] = *reinterpret_cast<const bf16x8*>(&bs[(brow + n * 16 + lr) * 64 + c16 * 8]);
            #pragma unroll
            for (int m = 0; m < 4; ++m)
                #pragma unroll
                for (int n = 0; n < 2; ++n)
                    acc[m][n] = __builtin_amdgcn_mfma_f32_16x16x32_bf16(af[m], bf[n], acc[m][n], 0, 0, 0);
        }
        if (kt + 1 < NKT) __syncthreads();
    }

    #pragma unroll
    for (int n = 0; n < 2; ++n) {
        const int cl  = brow + n * 16 + lr;
        const int col = ocol0 + cl;
        const float bcol = biast[cl];
        #pragma unroll
        for (int m = 0; m < 4; ++m) {
            #pragma unroll
            for (int r = 0; r < 4; ++r) {
                const int row = m0 + m * 16 + lk * 4 + r;
                float v = acc[m][n][r] + bcol;
                if (MODE == 0) {
                    ((unsigned short*)outp)[(size_t)row * ldo + col] = f2b(v);
                } else if (MODE == 1) {
                    ((unsigned short*)outp)[(size_t)row * ldo + col] = f2b(gelu_f(v));
                } else {
                    v += res[(size_t)row * ldo + col];
                    ((float*)outp)[(size_t)row * ldo + col] = v;
                }
            }
        }
    }
}

// XCD-swizzled 1D-grid tile maps, column-fastest (T1). Requires nwg % 8 == 0.
template<int NC, int TS>
DEV void tile_map(int& m0, int& n0){
    const int nwg = gridDim.x;
    const int lin = blockIdx.x;
    const int tile = (lin & 7) * (nwg >> 3) + (lin >> 3);
    m0 = (tile / NC) * TS;
    n0 = (tile % NC) * TS;
}
template<int NC, int TSM, int TSN>
DEV void tile_map2(int& m0, int& n0){
    const int nwg = gridDim.x;
    const int lin = blockIdx.x;
    const int tile = (lin & 7) * (nwg >> 3) + (lin >> 3);
    m0 = (tile / NC) * TSM;
    n0 = (tile % NC) * TSN;
}

// Fused Q/K/V GEMM at 64x128: N=768, A = tn for Q cols (n0<256), xb for K/V.
__global__ __launch_bounds__(256, 3)
void qkv_kernel(const unsigned short* __restrict__ tn,
                const unsigned short* __restrict__ xb,
                const unsigned short* __restrict__ WT,    // [768][256]
                const float* __restrict__ bqkv,           // [768]
                unsigned short* __restrict__ QKV)         // [8192][768]
{
    __shared__ unsigned short As[2][4096], Bs[2][8192];
    int m0, n0; tile_map2<6, 64, 128>(m0, n0);
    const unsigned short* A = (n0 < 256) ? tn : xb;
    gemm_bodyN128<256, 0>(A, m0, WT + (size_t)n0 * 256,
                          bqkv + n0, nullptr, QKV, 768, n0, As, Bs);
}

// W1 GEMM at 64x128 with GELU epilogue.
__global__ __launch_bounds__(256, 3)
void w1_kernel(const unsigned short* __restrict__ tn2,
               const unsigned short* __restrict__ W1T,    // [1024][256]
               const float* __restrict__ bf1,
               unsigned short* __restrict__ Hb)           // [8192][1024]
{
    __shared__ unsigned short As[2][4096], Bs[2][8192];
    int m0, n0; tile_map2<8, 64, 128>(m0, n0);
    gemm_bodyN128<256, 1>(tn2, m0, W1T + (size_t)n0 * 256,
                          bf1 + n0, nullptr, Hb, 1024, n0, As, Bs);
}

template<int K, int MODE, int NC>
__global__ __launch_bounds__(256)
void gemm_kernel(const unsigned short* __restrict__ A,
                 const unsigned short* __restrict__ BT,
                 const float* __restrict__ bias,
                 const float* __restrict__ res,
                 void* __restrict__ outp, int ldo)
{
    __shared__ unsigned short As[2][4096], Bs[2][4096];
    int m0, n0; tile_map<NC, 64>(m0, n0);
    gemm_body<K, MODE>(A, m0, BT + (size_t)n0 * K,
                       bias + n0, res, outp, ldo, n0, As, Bs);
}

// ---------------------------------------------------- Wo GEMM + residual + LN2
// Tile 32 x 256 (FULL output width per block -> block owns complete rows, so
// LN2 fuses in): t = AO@Wo + bo + x, Tf = t (f32), tn2 = LN(t) (bf16).
// 4 waves, wave w owns cols [w*64, w*64+64); acc[2][4] (32 VGPR). BK=64 dbuf.
// LN: intra-16-lane shfl butterfly (wave's 64-col slice) + LDS cross-wave.
__global__ __launch_bounds__(256, 2)
void wo_ln_kernel(const unsigned short* __restrict__ AOb,
                  const unsigned short* __restrict__ WOT,    // [256][256]
                  const float* __restrict__ bo,
                  const float* __restrict__ x,               // residual f32
                  const float* __restrict__ g2, const float* __restrict__ b2,
                  float* __restrict__ Tf,
                  unsigned short* __restrict__ tn2)
{
    __shared__ unsigned short As[2][2048];     // 32 x 64
    __shared__ unsigned short Bs[2][16384];    // 256 x 64
    __shared__ float2 red[4][32];              // [wave][row] {sum, sumsq}

    const int lin = blockIdx.x;
    const int m0  = ((lin & 7) * (gridDim.x >> 3) + (lin >> 3)) * 32;

    const int tid  = threadIdx.x;
    const int lane = tid & 63, wid = tid >> 6;
    const int srow = tid >> 3;                 // 0..31
    const int schk = (tid & 7) ^ (srow & 7);

    const unsigned short* Ag = AOb + (size_t)(m0 + srow) * 256 + schk * 8;
    const unsigned short* Bg = WOT + (size_t)srow        * 256 + schk * 8;

    const int wbase = __builtin_amdgcn_readfirstlane(wid) * 512;

    gload16(Ag, &As[0][wbase]);
    #pragma unroll
    for (int i = 0; i < 8; ++i)
        gload16(Bg + (size_t)(32 * i) * 256, &Bs[0][i * 2048 + wbase]);
    __syncthreads();

    f32x4 acc[2][4] = {};
    const int lr = lane & 15, lk = lane >> 4;
    const int sw = lr & 7;
    const int wc = wid * 64;                   // wave's col base

    for (int kt = 0; kt < 4; ++kt) {
        if (kt < 3) {
            const int nb = (kt + 1) & 1;
            gload16(Ag + (kt + 1) * 64, &As[nb][wbase]);
            #pragma unroll
            for (int i = 0; i < 8; ++i)
                gload16(Bg + (size_t)(32 * i) * 256 + (kt + 1) * 64, &Bs[nb][i * 2048 + wbase]);
        }
        const unsigned short* as = As[kt & 1];
        const unsigned short* bs = Bs[kt & 1];
        #pragma unroll
        for (int ks = 0; ks < 2; ++ks) {
            const int c16 = (ks * 4 + lk) ^ sw;
            bf16x8 af[2], bf[4];
            #pragma unroll
            for (int m = 0; m < 2; ++m)
                af[m] = *reinterpret_cast<const bf16x8*>(&as[(m * 16 + lr) * 64 + c16 * 8]);
            #pragma unroll
            for (int n = 0; n < 4; ++n)
                bf[n] = *reinterpret_cast<const bf16x8*>(&bs[(wc + n * 16 + lr) * 64 + c16 * 8]);
            #pragma unroll
            for (int m = 0; m < 2; ++m)
                #pragma unroll
                for (int n = 0; n < 4; ++n)
                    acc[m][n] = __builtin_amdgcn_mfma_f32_16x16x32_bf16(af[m], bf[n], acc[m][n], 0, 0, 0);
        }
        if (kt < 3) __syncthreads();
    }

    // epilogue: v = acc + bo + x; accumulate into acc in place
    #pragma unroll
    for (int n = 0; n < 4; ++n) {
        const int col = wc + n * 16 + lr;
        const float bcol = bo[col];
        #pragma unroll
        for (int m = 0; m < 2; ++m) {
            #pragma unroll
            for (int r = 0; r < 4; ++r) {
                const int row = m0 + m * 16 + lk * 4 + r;
                acc[m][n][r] += bcol + x[(size_t)row * 256 + col];
            }
        }
    }

    // per-row partial sums over the wave's 64-col slice
    float s1[2][4], s2[2][4];
    #pragma unroll
    for (int m = 0; m < 2; ++m)
        #pragma unroll
        for (int r = 0; r < 4; ++r) {
            float a = 0.f, b = 0.f;
            #pragma unroll
            for (int n = 0; n < 4; ++n) { const float v = acc[m][n][r]; a += v; b += v * v; }
            s1[m][r] = a; s2[m][r] = b;
        }
    #pragma unroll
    for (int mask = 1; mask <= 8; mask <<= 1)
        #pragma unroll
        for (int m = 0; m < 2; ++m)
            #pragma unroll
            for (int r = 0; r < 4; ++r) {
                s1[m][r] += __shfl_xor(s1[m][r], mask);
                s2[m][r] += __shfl_xor(s2[m][r], mask);
            }
    if (lr == 0) {
        #pragma unroll
        for (int m = 0; m < 2; ++m)
            #pragma unroll
            for (int r = 0; r < 4; ++r)
                red[wid][m * 16 + lk * 4 + r] = make_float2(s1[m][r], s2[m][r]);
    }
    __syncthreads();

    float mean[2][4], rstd[2][4];
    #pragma unroll
    for (int m = 0; m < 2; ++m)
        #pragma unroll
        for (int r = 0; r < 4; ++r) {
            const int rl = m * 16 + lk * 4 + r;
            float a = 0.f, b = 0.f;
            #pragma unroll
            for (int w4 = 0; w4 < 4; ++w4) { const float2 p = red[w4][rl]; a += p.x; b += p.y; }
            const float mu = a * (1.0f / 256.0f);
            mean[m][r] = mu;
            rstd[m][r] = rsqrtf(b * (1.0f / 256.0f) - mu * mu + 1e-5f);
        }

    #pragma unroll
    for (int n = 0; n < 4; ++n) {
        const int col = wc + n * 16 + lr;
        const float gc = g2[col], bc = b2[col];
        #pragma unroll
        for (int m = 0; m < 2; ++m) {
            #pragma unroll
            for (int r = 0; r < 4; ++r) {
                const int row = m0 + m * 16 + lk * 4 + r;
                const float v = acc[m][n][r];
                Tf[(size_t)row * 256 + col] = v;
                tn2[(size_t)row * 256 + col] =
                    f2b((v - mean[m][r]) * rstd[m][r] * gc + bc);
            }
        }
    }
}

// ---------------------------------------------------------------- attention
// Thread = (voxel, head, quarter), 16 waves/CU, online softmax per 9-group.
// V loads HOISTED next to K loads (18 outstanding) so V latency hides under
// the dot/shfl/softmax chain. No branches; invalid -> -inf -> p = 0.
// QKV layout: [NROW][768] bf16: Q (pre-scaled) 0..255, K 256..511, V 512..767.
DEV float dot8(uint4 u, const float* q){
    float s;
    s = q[0] * blo(u.x);          s = fmaf(q[1], bhi(u.x), s);
    s = fmaf(q[2], blo(u.y), s);  s = fmaf(q[3], bhi(u.y), s);
    s = fmaf(q[4], blo(u.z), s);  s = fmaf(q[5], bhi(u.z), s);
    s = fmaf(q[6], blo(u.w), s);  s = fmaf(q[7], bhi(u.w), s);
    return s;
}

__global__ __launch_bounds__(256, 4)
void attn_kernel(const unsigned short* __restrict__ QKV,
                 unsigned short* __restrict__ AO)
{
    const int t   = blockIdx.x * 256 + threadIdx.x;
    const int vox = t >> 5;                 // 32 threads per voxel
    const int ch  = (t & 31) * 8;           // head*32 + quarter*8
    const int d = (vox >> 8) & 15, h = (vox >> 4) & 15, w = vox & 15;

    float q[8];
    {
        uint4 u = *reinterpret_cast<const uint4*>(&QKV[(size_t)vox * 768 + ch]);
        q[0]=blo(u.x); q[1]=bhi(u.x); q[2]=blo(u.y); q[3]=bhi(u.y);
        q[4]=blo(u.z); q[5]=bhi(u.z); q[6]=blo(u.w); q[7]=bhi(u.w);
    }

    float mrun = -1e30f, z = 0.0f;
    float acc[8] = {};

    #pragma unroll
    for (int g = 0; g < 3; ++g) {
        const int di = g - 1;
        const int nd = d + di;
        unsigned vm = 0;
        uint4 ku[9], vu[9];
        #pragma unroll
        for (int j = 0; j < 9; ++j) {
            const int hi2 = j / 3 - 1, wi = j % 3 - 1;
            const int nh = h + hi2, nw = w + wi;
            const bool valid = !(di == 0 && hi2 == 0 && wi == 0) &&
                               ((unsigned)nd < 16u) && ((unsigned)nh < 16u) &&
                               ((unsigned)nw < 16u);
            const int r = valid ? ((vox & 4096) | (nd << 8) | (nh << 4) | nw) : vox;
            vm |= (unsigned)valid << j;
            const unsigned short* base = &QKV[(size_t)r * 768 + 256 + ch];
            ku[j] = *reinterpret_cast<const uint4*>(base);
            vu[j] = *reinterpret_cast<const uint4*>(base + 256);
        }

        float s9[9];
        #pragma unroll
        for (int j = 0; j < 9; ++j) {
            float s = dot8(ku[j], q);
            s += __shfl_xor(s, 1);          // quad-perm DPP (VALU pipe)
            s += __shfl_xor(s, 2);
            s9[j] = ((vm >> j) & 1u) ? s : -INFINITY;
        }

        float gm = s9[0];
        #pragma unroll
        for (int j = 1; j < 9; ++j) gm = fmaxf(gm, s9[j]);
        const float nm = fmaxf(mrun, gm);   // finite always
        const float rs = __expf(mrun - nm);
        mrun = nm;
        z *= rs;
        #pragma unroll
        for (int i = 0; i < 8; ++i) acc[i] *= rs;

        #pragma unroll
        for (int j = 0; j < 9; ++j) {
            const float p = __expf(s9[j] - nm);   // -inf -> exactly 0
            z += p;
            const uint4 u = vu[j];
            acc[0] = fmaf(p, blo(u.x), acc[0]); acc[1] = fmaf(p, bhi(u.x), acc[1]);
            acc[2] = fmaf(p, blo(u.y), acc[2]); acc[3] = fmaf(p, bhi(u.y), acc[3]);
            acc[4] = fmaf(p, blo(u.z), acc[4]); acc[5] = fmaf(p, bhi(u.z), acc[5]);
            acc[6] = fmaf(p, blo(u.w), acc[6]); acc[7] = fmaf(p, bhi(u.w), acc[7]);
        }
    }

    const float inv = 1.0f / z;
    uint4 o;
    o.x = (unsigned)f2b(acc[0] * inv) | ((unsigned)f2b(acc[1] * inv) << 16);
    o.y = (unsigned)f2b(acc[2] * inv) | ((unsigned)f2b(acc[3] * inv) << 16);
    o.z = (unsigned)f2b(acc[4] * inv) | ((unsigned)f2b(acc[5] * inv) << 16);
    o.w = (unsigned)f2b(acc[6] * inv) | ((unsigned)f2b(acc[7] * inv) << 16);
    *reinterpret_cast<uint4*>(&AO[(size_t)vox * C + ch]) = o;
}

// ---------------------------------------------------------------- launch
extern "C" void kernel_launch(void* const* d_in, const int* in_sizes, int n_in,
                              void* d_out, int out_size, void* d_ws, size_t ws_size,
                              hipStream_t stream)
{
    const float* x   = (const float*)d_in[0];
    const float* Wq  = (const float*)d_in[1];
    const float* bq  = (const float*)d_in[2];
    const float* Wk  = (const float*)d_in[3];
    const float* bk  = (const float*)d_in[4];
    const float* Wv  = (const float*)d_in[5];
    const float* bv  = (const float*)d_in[6];
    const float* Wo  = (const float*)d_in[7];
    const float* bo  = (const float*)d_in[8];
    const float* g1  = (const float*)d_in[9];
    const float* b1  = (const float*)d_in[10];
    const float* g2  = (const float*)d_in[11];
    const float* b2  = (const float*)d_in[12];
    const float* W1  = (const float*)d_in[13];
    const float* bf1 = (const float*)d_in[14];
    const float* W2  = (const float*)d_in[15];
    const float* bf2 = (const float*)d_in[16];

    char* ws = (char*)d_ws;
    size_t o = 0;
    unsigned short* WQT = (unsigned short*)(ws + o); o += (size_t)256 * 256 * 2;   // [768][256] with WKT/WVT
    unsigned short* WKT = (unsigned short*)(ws + o); o += (size_t)256 * 256 * 2;
    unsigned short* WVT = (unsigned short*)(ws + o); o += (size_t)256 * 256 * 2;
    unsigned short* WOT = (unsigned short*)(ws + o); o += (size_t)256 * 256 * 2;
    unsigned short* W1T = (unsigned short*)(ws + o); o += (size_t)256 * 1024 * 2;
    unsigned short* W2T = (unsigned short*)(ws + o); o += (size_t)1024 * 256 * 2;
    float*          bqkv= (float*)(ws + o);          o += (size_t)768 * 4;
    unsigned short* tn  = (unsigned short*)(ws + o); o += (size_t)NROW * C * 2;
    unsigned short* xb  = (unsigned short*)(ws + o); o += (size_t)NROW * C * 2;
    unsigned short* QKVb= (unsigned short*)(ws + o); o += (size_t)NROW * 768 * 2;
    unsigned short* AOb = (unsigned short*)(ws + o); o += (size_t)NROW * C * 2;
    float*          Tf  = (float*)(ws + o);          o += (size_t)NROW * C * 4;
    unsigned short* tn2 = (unsigned short*)(ws + o); o += (size_t)NROW * C * 2;
    unsigned short* Hb  = (unsigned short*)(ws + o); o += (size_t)NROW * F * 2;

    prep_ln_kernel<<<193 + NROW / 4, 256, 0, stream>>>(Wq, Wk, Wv, Wo, W1, W2, bq, bk, bv,
                                                       WQT, WKT, WVT, WOT, W1T, W2T, bqkv,
                                                       x, g1, b1, tn, xb);

    qkv_kernel<<<(NROW / 64) * 6, 256, 0, stream>>>(tn, xb, WQT, bqkv, QKVb);

    attn_kernel<<<NROW * 32 / 256, 256, 0, stream>>>(QKVb, AOb);

    wo_ln_kernel<<<NROW / 32, 256, 0, stream>>>(AOb, WOT, bo, x, g2, b2, Tf, tn2);

    w1_kernel<<<(NROW / 64) * 8, 256, 0, stream>>>(tn2, W1T, bf1, Hb);

    gemm_kernel<1024, 2, 4><<<(NROW / 64) * 4, 256, 0, stream>>>(Hb, W2T, bf2, Tf, (float*)d_out, 256);
}

// Round 14
// 74.104 us; speedup vs baseline: 1.0955x; 1.0057x over previous
//
#include <hip/hip_runtime.h>

typedef __bf16 bf16x8 __attribute__((ext_vector_type(8)));
typedef float f32x4 __attribute__((ext_vector_type(4)));

#define DEV static __device__ __forceinline__

DEV unsigned short f2b(float f){
    unsigned int u = __float_as_uint(f);
    u += 0x7fffu + ((u >> 16) & 1u);
    return (unsigned short)(u >> 16);
}
DEV float b2f(unsigned short h){ return __uint_as_float(((unsigned int)h) << 16); }
DEV float blo(unsigned int u){ return __uint_as_float(u << 16); }
DEV float bhi(unsigned int u){ return __uint_as_float(u & 0xffff0000u); }
DEV float gelu_f(float x){ return 0.5f * x * (1.0f + erff(x * 0.7071067811865476f)); }

// async global->LDS, 16B per lane, wave-uniform LDS base (HW adds lane*16).
DEV void gload16(const unsigned short* g, unsigned short* l){
    __builtin_amdgcn_global_load_lds(
        (const __attribute__((address_space(1))) void*)g,
        (__attribute__((address_space(3))) void*)l, 16, 0, 0);
}

// ---------------------------------------------------------------- constants
static constexpr int NROW = 8192;   // B*D*H*W = 2*16*16*16
static constexpr int C    = 256;
static constexpr int F    = 1024;
static constexpr float ATT_SCALE = 0.17677669529663688f;   // 1/sqrt(32)

// ---------------------------------------------------------------- prep + LN1
__global__ __launch_bounds__(256)
void prep_ln_kernel(const float* __restrict__ Wq, const float* __restrict__ Wk,
                    const float* __restrict__ Wv, const float* __restrict__ Wo,
                    const float* __restrict__ W1, const float* __restrict__ W2,
                    const float* __restrict__ bq, const float* __restrict__ bk,
                    const float* __restrict__ bv,
                    unsigned short* __restrict__ WQT, unsigned short* __restrict__ WKT,
                    unsigned short* __restrict__ WVT, unsigned short* __restrict__ WOT,
                    unsigned short* __restrict__ W1T, unsigned short* __restrict__ W2T,
                    float* __restrict__ bqkv,
                    const float* __restrict__ x, const float* __restrict__ g1,
                    const float* __restrict__ b1,
                    unsigned short* __restrict__ tn, unsigned short* __restrict__ xb)
{
    const int tid = threadIdx.x;
    if (blockIdx.x < 192) {
        __shared__ unsigned short T[64][66];
        const int t = blockIdx.x;
        const float* src; unsigned short* dst;
        int ldw, ldt, r0, c0; float sc = 1.0f;
        if (t < 64) {                       // 4 square 256x256 mats, 16 tiles each
            const int m = t >> 4, sub = t & 15;
            src = (m == 0) ? Wq : (m == 1) ? Wk : (m == 2) ? Wv : Wo;
            dst = (m == 0) ? WQT : (m == 1) ? WKT : (m == 2) ? WVT : WOT;
            if (m == 0) sc = ATT_SCALE;
            ldw = 256; ldt = 256;
            r0 = (sub >> 2) * 64; c0 = (sub & 3) * 64;
        } else if (t < 128) {               // W1: 256x1024 -> W1T [1024][256]
            const int sub = t - 64;
            src = W1; dst = W1T; ldw = 1024; ldt = 256;
            r0 = (sub >> 4) * 64; c0 = (sub & 15) * 64;
        } else {                            // W2: 1024x256 -> W2T [256][1024]
            const int sub = t - 128;
            src = W2; dst = W2T; ldw = 256; ldt = 1024;
            r0 = (sub >> 2) * 64; c0 = (sub & 3) * 64;
        }
        #pragma unroll
        for (int i = 0; i < 16; ++i) {
            const int rl = i * 4 + (tid >> 6), cl = tid & 63;
            T[rl][cl] = f2b(src[(size_t)(r0 + rl) * ldw + c0 + cl] * sc);
        }
        __syncthreads();
        #pragma unroll
        for (int j = 0; j < 16; ++j) {
            const int cl = j * 4 + (tid >> 6), rl = tid & 63;
            dst[(size_t)(c0 + cl) * ldt + r0 + rl] = T[rl][cl];
        }
    } else if (blockIdx.x == 192) {
        #pragma unroll
        for (int i = 0; i < 3; ++i) {
            const int v = i * 256 + tid;
            bqkv[v] = (v < 256) ? bq[v] * ATT_SCALE
                    : (v < 512) ? bk[v - 256] : bv[v - 512];
        }
    } else {
        const int row  = (blockIdx.x - 193) * 4 + (tid >> 6);
        const int lane = tid & 63;
        float4 v = ((const float4*)(x + (size_t)row * C))[lane];
        float s = v.x + v.y + v.z + v.w;
        #pragma unroll
        for (int m = 32; m >= 1; m >>= 1) s += __shfl_xor(s, m);
        const float mean = s * (1.0f / 256.0f);
        const float d0 = v.x - mean, d1 = v.y - mean, d2 = v.z - mean, d3 = v.w - mean;
        float s2 = d0 * d0 + d1 * d1 + d2 * d2 + d3 * d3;
        #pragma unroll
        for (int m = 32; m >= 1; m >>= 1) s2 += __shfl_xor(s2, m);
        const float rstd = rsqrtf(s2 * (1.0f / 256.0f) + 1e-5f);
        float4 gg = ((const float4*)g1)[lane];
        float4 bb = ((const float4*)b1)[lane];
        ushort4 o = { f2b(d0 * rstd * gg.x + bb.x), f2b(d1 * rstd * gg.y + bb.y),
                      f2b(d2 * rstd * gg.z + bb.z), f2b(d3 * rstd * gg.w + bb.w) };
        ((ushort4*)(tn + (size_t)row * C))[lane] = o;
        ushort4 xo = { f2b(v.x), f2b(v.y), f2b(v.z), f2b(v.w) };
        ((ushort4*)(xb + (size_t)row * C))[lane] = xo;
    }
}

// ---------------------------------------------------------------- 64x64 GEMM
// (kept for W2: K=1024, N=256)
template<int K, int MODE>
DEV void gemm_body(const unsigned short* __restrict__ A, int m0,
                   const unsigned short* __restrict__ BTt,
                   const float* __restrict__ biast,
                   const float* __restrict__ res, void* __restrict__ outp,
                   int ldo, int ocol0,
                   unsigned short (&As)[2][4096], unsigned short (&Bs)[2][4096])
{
    constexpr int BK = 64, NKT = K / BK;
    const int tid  = threadIdx.x;
    const int lane = tid & 63, wid = tid >> 6;
    const int srow = tid >> 3;                    // 0..31
    const int schk = (tid & 7) ^ (srow & 7);      // inverse-swizzled src chunk

    const unsigned short* Ag = A   + (size_t)(m0 + srow) * K + schk * 8;
    const unsigned short* Bg = BTt + (size_t)srow        * K + schk * 8;

    const int wbase = __builtin_amdgcn_readfirstlane(wid) * 512;

    gload16(Ag,          &As[0][wbase]);
    gload16(Ag + 32 * K, &As[0][wbase + 2048]);
    gload16(Bg,          &Bs[0][wbase]);
    gload16(Bg + 32 * K, &Bs[0][wbase + 2048]);
    __syncthreads();

    f32x4 acc[4] = {};
    const int lr = lane & 15, lk = lane >> 4;
    const int sw = lr & 7;

    for (int kt = 0; kt < NKT; ++kt) {
        if (kt + 1 < NKT) {
            const int nb = (kt + 1) & 1;
            gload16(Ag + (kt + 1) * BK,          &As[nb][wbase]);
            gload16(Ag + 32 * K + (kt + 1) * BK, &As[nb][wbase + 2048]);
            gload16(Bg + (kt + 1) * BK,          &Bs[nb][wbase]);
            gload16(Bg + 32 * K + (kt + 1) * BK, &Bs[nb][wbase + 2048]);
        }
        const unsigned short* as = As[kt & 1];
        const unsigned short* bs = Bs[kt & 1];
        #pragma unroll
        for (int s = 0; s < 2; ++s) {
            const int c16 = (s * 4 + lk) ^ sw;
            bf16x8 bfr = *reinterpret_cast<const bf16x8*>(&bs[(wid * 16 + lr) * 64 + c16 * 8]);
            #pragma unroll
            for (int m = 0; m < 4; ++m) {
                bf16x8 afr = *reinterpret_cast<const bf16x8*>(&as[(m * 16 + lr) * 64 + c16 * 8]);
                acc[m] = __builtin_amdgcn_mfma_f32_16x16x32_bf16(afr, bfr, acc[m], 0, 0, 0);
            }
        }
        if (kt + 1 < NKT) __syncthreads();
    }

    const int col  = ocol0 + wid * 16 + lr;
    const float bcol = biast[wid * 16 + lr];
    #pragma unroll
    for (int m = 0; m < 4; ++m) {
        #pragma unroll
        for (int r = 0; r < 4; ++r) {
            const int row = m0 + m * 16 + lk * 4 + r;
            float v = acc[m][r] + bcol;
            if (MODE == 0) {
                ((unsigned short*)outp)[(size_t)row * ldo + col] = f2b(v);
            } else if (MODE == 1) {
                ((unsigned short*)outp)[(size_t)row * ldo + col] = f2b(gelu_f(v));
            } else {
                v += res[(size_t)row * ldo + col];
                ((float*)outp)[(size_t)row * ldo + col] = v;
            }
        }
    }
}

// ---------------------------------------------------------------- 64x128 GEMM
template<int K, int MODE>
DEV void gemm_bodyN128(const unsigned short* __restrict__ A, int m0,
                       const unsigned short* __restrict__ BTt,  // BT + n0*K
                       const float* __restrict__ biast,
                       const float* __restrict__ res, void* __restrict__ outp,
                       int ldo, int ocol0,
                       unsigned short (&As)[2][4096], unsigned short (&Bs)[2][8192])
{
    constexpr int BK = 64, NKT = K / BK;
    const int tid  = threadIdx.x;
    const int lane = tid & 63, wid = tid >> 6;
    const int srow = tid >> 3;                    // 0..31
    const int schk = (tid & 7) ^ (srow & 7);

    const unsigned short* Ag = A   + (size_t)(m0 + srow) * K + schk * 8;
    const unsigned short* Bg = BTt + (size_t)srow        * K + schk * 8;

    const int wbase = __builtin_amdgcn_readfirstlane(wid) * 512;

    gload16(Ag,          &As[0][wbase]);
    gload16(Ag + 32 * K, &As[0][wbase + 2048]);
    #pragma unroll
    for (int i = 0; i < 4; ++i)
        gload16(Bg + (size_t)(32 * i) * K, &Bs[0][i * 2048 + wbase]);
    __syncthreads();

    f32x4 acc[4][2] = {};
    const int lr = lane & 15, lk = lane >> 4;
    const int sw = lr & 7;
    const int brow = wid * 32;                    // wave's B-row (output col) base

    for (int kt = 0; kt < NKT; ++kt) {
        if (kt + 1 < NKT) {
            const int nb = (kt + 1) & 1;
            gload16(Ag + (kt + 1) * BK,          &As[nb][wbase]);
            gload16(Ag + 32 * K + (kt + 1) * BK, &As[nb][wbase + 2048]);
            #pragma unroll
            for (int i = 0; i < 4; ++i)
                gload16(Bg + (size_t)(32 * i) * K + (kt + 1) * BK, &Bs[nb][i * 2048 + wbase]);
        }
        const unsigned short* as = As[kt & 1];
        const unsigned short* bs = Bs[kt & 1];
        #pragma unroll
        for (int ks = 0; ks < 2; ++ks) {
            const int c16 = (ks * 4 + lk) ^ sw;
            bf16x8 af[4], bf[2];
            #pragma unroll
            for (int m = 0; m < 4; ++m)
                af[m] = *reinterpret_cast<const bf16x8*>(&as[(m * 16 + lr) * 64 + c16 * 8]);
            #pragma unroll
            for (int n = 0; n < 2; ++n)
                bf[n] = *reinterpret_cast<const bf16x8*>(&bs[(brow + n * 16 + lr) * 64 + c16 * 8]);
            #pragma unroll
            for (int m = 0; m < 4; ++m)
                #pragma unroll
                for (int n = 0; n < 2; ++n)
                    acc[m][n] = __builtin_amdgcn_mfma_f32_16x16x32_bf16(af[m], bf[n], acc[m][n], 0, 0, 0);
        }
        if (kt + 1 < NKT) __syncthreads();
    }

    #pragma unroll
    for (int n = 0; n < 2; ++n) {
        const int cl  = brow + n * 16 + lr;
        const int col = ocol0 + cl;
        const float bcol = biast[cl];
        #pragma unroll
        for (int m = 0; m < 4; ++m) {
            #pragma unroll
            for (int r = 0; r < 4; ++r) {
                const int row = m0 + m * 16 + lk * 4 + r;
                float v = acc[m][n][r] + bcol;
                if (MODE == 0) {
                    ((unsigned short*)outp)[(size_t)row * ldo + col] = f2b(v);
                } else if (MODE == 1) {
                    ((unsigned short*)outp)[(size_t)row * ldo + col] = f2b(gelu_f(v));
                } else {
                    v += res[(size_t)row * ldo + col];
                    ((float*)outp)[(size_t)row * ldo + col] = v;
                }
            }
        }
    }
}

// XCD-swizzled 1D-grid tile maps, column-fastest (T1). Requires nwg % 8 == 0.
template<int NC, int TS>
DEV void tile_map(int& m0, int& n0){
    const int nwg = gridDim.x;
    const int lin = blockIdx.x;
    const int tile = (lin & 7) * (nwg >> 3) + (lin >> 3);
    m0 = (tile / NC) * TS;
    n0 = (tile % NC) * TS;
}
template<int NC, int TSM, int TSN>
DEV void tile_map2(int& m0, int& n0){
    const int nwg = gridDim.x;
    const int lin = blockIdx.x;
    const int tile = (lin & 7) * (nwg >> 3) + (lin >> 3);
    m0 = (tile / NC) * TSM;
    n0 = (tile % NC) * TSN;
}

// Fused Q/K/V GEMM at 64x128: N=768, A = tn for Q cols (n0<256), xb for K/V.
__global__ __launch_bounds__(256, 3)
void qkv_kernel(const unsigned short* __restrict__ tn,
                const unsigned short* __restrict__ xb,
                const unsigned short* __restrict__ WT,    // [768][256]
                const float* __restrict__ bqkv,           // [768]
                unsigned short* __restrict__ QKV)         // [8192][768]
{
    __shared__ unsigned short As[2][4096], Bs[2][8192];
    int m0, n0; tile_map2<6, 64, 128>(m0, n0);
    const unsigned short* A = (n0 < 256) ? tn : xb;
    gemm_bodyN128<256, 0>(A, m0, WT + (size_t)n0 * 256,
                          bqkv + n0, nullptr, QKV, 768, n0, As, Bs);
}

// W1 GEMM at 64x128 with GELU epilogue.
__global__ __launch_bounds__(256, 3)
void w1_kernel(const unsigned short* __restrict__ tn2,
               const unsigned short* __restrict__ W1T,    // [1024][256]
               const float* __restrict__ bf1,
               unsigned short* __restrict__ Hb)           // [8192][1024]
{
    __shared__ unsigned short As[2][4096], Bs[2][8192];
    int m0, n0; tile_map2<8, 64, 128>(m0, n0);
    gemm_bodyN128<256, 1>(tn2, m0, W1T + (size_t)n0 * 256,
                          bf1 + n0, nullptr, Hb, 1024, n0, As, Bs);
}

template<int K, int MODE, int NC>
__global__ __launch_bounds__(256)
void gemm_kernel(const unsigned short* __restrict__ A,
                 const unsigned short* __restrict__ BT,
                 const float* __restrict__ bias,
                 const float* __restrict__ res,
                 void* __restrict__ outp, int ldo)
{
    __shared__ unsigned short As[2][4096], Bs[2][4096];
    int m0, n0; tile_map<NC, 64>(m0, n0);
    gemm_body<K, MODE>(A, m0, BT + (size_t)n0 * K,
                       bias + n0, res, outp, ldo, n0, As, Bs);
}

// ---------------------------------------------------- Wo GEMM + residual + LN2
// Tile 32 x 256 (FULL output width per block -> block owns complete rows, so
// LN2 fuses in): t = AO@Wo + bo + x, Tf = t (f32), tn2 = LN(t) (bf16).
__global__ __launch_bounds__(256, 2)
void wo_ln_kernel(const unsigned short* __restrict__ AOb,
                  const unsigned short* __restrict__ WOT,    // [256][256]
                  const float* __restrict__ bo,
                  const float* __restrict__ x,               // residual f32
                  const float* __restrict__ g2, const float* __restrict__ b2,
                  float* __restrict__ Tf,
                  unsigned short* __restrict__ tn2)
{
    __shared__ unsigned short As[2][2048];     // 32 x 64
    __shared__ unsigned short Bs[2][16384];    // 256 x 64
    __shared__ float2 red[4][32];              // [wave][row] {sum, sumsq}

    const int lin = blockIdx.x;
    const int m0  = ((lin & 7) * (gridDim.x >> 3) + (lin >> 3)) * 32;

    const int tid  = threadIdx.x;
    const int lane = tid & 63, wid = tid >> 6;
    const int srow = tid >> 3;                 // 0..31
    const int schk = (tid & 7) ^ (srow & 7);

    const unsigned short* Ag = AOb + (size_t)(m0 + srow) * 256 + schk * 8;
    const unsigned short* Bg = WOT + (size_t)srow        * 256 + schk * 8;

    const int wbase = __builtin_amdgcn_readfirstlane(wid) * 512;

    gload16(Ag, &As[0][wbase]);
    #pragma unroll
    for (int i = 0; i < 8; ++i)
        gload16(Bg + (size_t)(32 * i) * 256, &Bs[0][i * 2048 + wbase]);
    __syncthreads();

    f32x4 acc[2][4] = {};
    const int lr = lane & 15, lk = lane >> 4;
    const int sw = lr & 7;
    const int wc = wid * 64;                   // wave's col base

    for (int kt = 0; kt < 4; ++kt) {
        if (kt < 3) {
            const int nb = (kt + 1) & 1;
            gload16(Ag + (kt + 1) * 64, &As[nb][wbase]);
            #pragma unroll
            for (int i = 0; i < 8; ++i)
                gload16(Bg + (size_t)(32 * i) * 256 + (kt + 1) * 64, &Bs[nb][i * 2048 + wbase]);
        }
        const unsigned short* as = As[kt & 1];
        const unsigned short* bs = Bs[kt & 1];
        #pragma unroll
        for (int ks = 0; ks < 2; ++ks) {
            const int c16 = (ks * 4 + lk) ^ sw;
            bf16x8 af[2], bf[4];
            #pragma unroll
            for (int m = 0; m < 2; ++m)
                af[m] = *reinterpret_cast<const bf16x8*>(&as[(m * 16 + lr) * 64 + c16 * 8]);
            #pragma unroll
            for (int n = 0; n < 4; ++n)
                bf[n] = *reinterpret_cast<const bf16x8*>(&bs[(wc + n * 16 + lr) * 64 + c16 * 8]);
            #pragma unroll
            for (int m = 0; m < 2; ++m)
                #pragma unroll
                for (int n = 0; n < 4; ++n)
                    acc[m][n] = __builtin_amdgcn_mfma_f32_16x16x32_bf16(af[m], bf[n], acc[m][n], 0, 0, 0);
        }
        if (kt < 3) __syncthreads();
    }

    // epilogue: v = acc + bo + x
    #pragma unroll
    for (int n = 0; n < 4; ++n) {
        const int col = wc + n * 16 + lr;
        const float bcol = bo[col];
        #pragma unroll
        for (int m = 0; m < 2; ++m) {
            #pragma unroll
            for (int r = 0; r < 4; ++r) {
                const int row = m0 + m * 16 + lk * 4 + r;
                acc[m][n][r] += bcol + x[(size_t)row * 256 + col];
            }
        }
    }

    // per-row partial sums over the wave's 64-col slice
    float s1[2][4], s2[2][4];
    #pragma unroll
    for (int m = 0; m < 2; ++m)
        #pragma unroll
        for (int r = 0; r < 4; ++r) {
            float a = 0.f, b = 0.f;
            #pragma unroll
            for (int n = 0; n < 4; ++n) { const float v = acc[m][n][r]; a += v; b += v * v; }
            s1[m][r] = a; s2[m][r] = b;
        }
    #pragma unroll
    for (int mask = 1; mask <= 8; mask <<= 1)
        #pragma unroll
        for (int m = 0; m < 2; ++m)
            #pragma unroll
            for (int r = 0; r < 4; ++r) {
                s1[m][r] += __shfl_xor(s1[m][r], mask);
                s2[m][r] += __shfl_xor(s2[m][r], mask);
            }
    if (lr == 0) {
        #pragma unroll
        for (int m = 0; m < 2; ++m)
            #pragma unroll
            for (int r = 0; r < 4; ++r)
                red[wid][m * 16 + lk * 4 + r] = make_float2(s1[m][r], s2[m][r]);
    }
    __syncthreads();

    float mean[2][4], rstd[2][4];
    #pragma unroll
    for (int m = 0; m < 2; ++m)
        #pragma unroll
        for (int r = 0; r < 4; ++r) {
            const int rl = m * 16 + lk * 4 + r;
            float a = 0.f, b = 0.f;
            #pragma unroll
            for (int w4 = 0; w4 < 4; ++w4) { const float2 p = red[w4][rl]; a += p.x; b += p.y; }
            const float mu = a * (1.0f / 256.0f);
            mean[m][r] = mu;
            rstd[m][r] = rsqrtf(b * (1.0f / 256.0f) - mu * mu + 1e-5f);
        }

    #pragma unroll
    for (int n = 0; n < 4; ++n) {
        const int col = wc + n * 16 + lr;
        const float gc = g2[col], bc = b2[col];
        #pragma unroll
        for (int m = 0; m < 2; ++m) {
            #pragma unroll
            for (int r = 0; r < 4; ++r) {
                const int row = m0 + m * 16 + lk * 4 + r;
                const float v = acc[m][n][r];
                Tf[(size_t)row * 256 + col] = v;
                tn2[(size_t)row * 256 + col] =
                    f2b((v - mean[m][r]) * rstd[m][r] * gc + bc);
            }
        }
    }
}

// ---------------------------------------------------------------- attention
// Thread = (voxel, head, quarter), 16 waves/CU, online softmax per 9-group,
// K+V loads hoisted (18 outstanding). NEW: XCD-swizzled block index — each
// XCD owns a contiguous 4-slice d-slab (1024 voxels); K/V slab + halo
// ~1.3 MB << 4 MB L2, so the 27x neighbor re-reads become L2 hits instead
// of thrashing to Infinity Cache (round-13 analysis: ~10 TB/s => L3-bound).
// QKV layout: [NROW][768] bf16: Q (pre-scaled) 0..255, K 256..511, V 512..767.
DEV float dot8(uint4 u, const float* q){
    float s;
    s = q[0] * blo(u.x);          s = fmaf(q[1], bhi(u.x), s);
    s = fmaf(q[2], blo(u.y), s);  s = fmaf(q[3], bhi(u.y), s);
    s = fmaf(q[4], blo(u.z), s);  s = fmaf(q[5], bhi(u.z), s);
    s = fmaf(q[6], blo(u.w), s);  s = fmaf(q[7], bhi(u.w), s);
    return s;
}

__global__ __launch_bounds__(256, 4)
void attn_kernel(const unsigned short* __restrict__ QKV,
                 unsigned short* __restrict__ AO)
{
    const int lin = blockIdx.x;
    const int sb  = (lin & 7) * (gridDim.x >> 3) + (lin >> 3);   // XCD slab map
    const int t   = sb * 256 + threadIdx.x;
    const int vox = t >> 5;                 // 32 threads per voxel
    const int ch  = (t & 31) * 8;           // head*32 + quarter*8
    const int d = (vox >> 8) & 15, h = (vox >> 4) & 15, w = vox & 15;

    float q[8];
    {
        uint4 u = *reinterpret_cast<const uint4*>(&QKV[(size_t)vox * 768 + ch]);
        q[0]=blo(u.x); q[1]=bhi(u.x); q[2]=blo(u.y); q[3]=bhi(u.y);
        q[4]=blo(u.z); q[5]=bhi(u.z); q[6]=blo(u.w); q[7]=bhi(u.w);
    }

    float mrun = -1e30f, z = 0.0f;
    float acc[8] = {};

    #pragma unroll
    for (int g = 0; g < 3; ++g) {
        const int di = g - 1;
        const int nd = d + di;
        unsigned vm = 0;
        uint4 ku[9], vu[9];
        #pragma unroll
        for (int j = 0; j < 9; ++j) {
            const int hi2 = j / 3 - 1, wi = j % 3 - 1;
            const int nh = h + hi2, nw = w + wi;
            const bool valid = !(di == 0 && hi2 == 0 && wi == 0) &&
                               ((unsigned)nd < 16u) && ((unsigned)nh < 16u) &&
                               ((unsigned)nw < 16u);
            const int r = valid ? ((vox & 4096) | (nd << 8) | (nh << 4) | nw) : vox;
            vm |= (unsigned)valid << j;
            const unsigned short* base = &QKV[(size_t)r * 768 + 256 + ch];
            ku[j] = *reinterpret_cast<const uint4*>(base);
            vu[j] = *reinterpret_cast<const uint4*>(base + 256);
        }

        float s9[9];
        #pragma unroll
        for (int j = 0; j < 9; ++j) {
            float s = dot8(ku[j], q);
            s += __shfl_xor(s, 1);          // quad-perm DPP (VALU pipe)
            s += __shfl_xor(s, 2);
            s9[j] = ((vm >> j) & 1u) ? s : -INFINITY;
        }

        float gm = s9[0];
        #pragma unroll
        for (int j = 1; j < 9; ++j) gm = fmaxf(gm, s9[j]);
        const float nm = fmaxf(mrun, gm);   // finite always
        const float rs = __expf(mrun - nm);
        mrun = nm;
        z *= rs;
        #pragma unroll
        for (int i = 0; i < 8; ++i) acc[i] *= rs;

        #pragma unroll
        for (int j = 0; j < 9; ++j) {
            const float p = __expf(s9[j] - nm);   // -inf -> exactly 0
            z += p;
            const uint4 u = vu[j];
            acc[0] = fmaf(p, blo(u.x), acc[0]); acc[1] = fmaf(p, bhi(u.x), acc[1]);
            acc[2] = fmaf(p, blo(u.y), acc[2]); acc[3] = fmaf(p, bhi(u.y), acc[3]);
            acc[4] = fmaf(p, blo(u.z), acc[4]); acc[5] = fmaf(p, bhi(u.z), acc[5]);
            acc[6] = fmaf(p, blo(u.w), acc[6]); acc[7] = fmaf(p, bhi(u.w), acc[7]);
        }
    }

    const float inv = 1.0f / z;
    uint4 o;
    o.x = (unsigned)f2b(acc[0] * inv) | ((unsigned)f2b(acc[1] * inv) << 16);
    o.y = (unsigned)f2b(acc[2] * inv) | ((unsigned)f2b(acc[3] * inv) << 16);
    o.z = (unsigned)f2b(acc[4] * inv) | ((unsigned)f2b(acc[5] * inv) << 16);
    o.w = (unsigned)f2b(acc[6] * inv) | ((unsigned)f2b(acc[7] * inv) << 16);
    *reinterpret_cast<uint4*>(&AO[(size_t)vox * C + ch]) = o;
}

// ---------------------------------------------------------------- launch
extern "C" void kernel_launch(void* const* d_in, const int* in_sizes, int n_in,
                              void* d_out, int out_size, void* d_ws, size_t ws_size,
                              hipStream_t stream)
{
    const float* x   = (const float*)d_in[0];
    const float* Wq  = (const float*)d_in[1];
    const float* bq  = (const float*)d_in[2];
    const float* Wk  = (const float*)d_in[3];
    const float* bk  = (const float*)d_in[4];
    const float* Wv  = (const float*)d_in[5];
    const float* bv  = (const float*)d_in[6];
    const float* Wo  = (const float*)d_in[7];
    const float* bo  = (const float*)d_in[8];
    const float* g1  = (const float*)d_in[9];
    const float* b1  = (const float*)d_in[10];
    const float* g2  = (const float*)d_in[11];
    const float* b2  = (const float*)d_in[12];
    const float* W1  = (const float*)d_in[13];
    const float* bf1 = (const float*)d_in[14];
    const float* W2  = (const float*)d_in[15];
    const float* bf2 = (const float*)d_in[16];

    char* ws = (char*)d_ws;
    size_t o = 0;
    unsigned short* WQT = (unsigned short*)(ws + o); o += (size_t)256 * 256 * 2;   // [768][256] with WKT/WVT
    unsigned short* WKT = (unsigned short*)(ws + o); o += (size_t)256 * 256 * 2;
    unsigned short* WVT = (unsigned short*)(ws + o); o += (size_t)256 * 256 * 2;
    unsigned short* WOT = (unsigned short*)(ws + o); o += (size_t)256 * 256 * 2;
    unsigned short* W1T = (unsigned short*)(ws + o); o += (size_t)256 * 1024 * 2;
    unsigned short* W2T = (unsigned short*)(ws + o); o += (size_t)1024 * 256 * 2;
    float*          bqkv= (float*)(ws + o);          o += (size_t)768 * 4;
    unsigned short* tn  = (unsigned short*)(ws + o); o += (size_t)NROW * C * 2;
    unsigned short* xb  = (unsigned short*)(ws + o); o += (size_t)NROW * C * 2;
    unsigned short* QKVb= (unsigned short*)(ws + o); o += (size_t)NROW * 768 * 2;
    unsigned short* AOb = (unsigned short*)(ws + o); o += (size_t)NROW * C * 2;
    float*          Tf  = (float*)(ws + o);          o += (size_t)NROW * C * 4;
    unsigned short* tn2 = (unsigned short*)(ws + o); o += (size_t)NROW * C * 2;
    unsigned short* Hb  = (unsigned short*)(ws + o); o += (size_t)NROW * F * 2;

    prep_ln_kernel<<<193 + NROW / 4, 256, 0, stream>>>(Wq, Wk, Wv, Wo, W1, W2, bq, bk, bv,
                                                       WQT, WKT, WVT, WOT, W1T, W2T, bqkv,
                                                       x, g1, b1, tn, xb);

    qkv_kernel<<<(NROW / 64) * 6, 256, 0, stream>>>(tn, xb, WQT, bqkv, QKVb);

    attn_kernel<<<NROW * 32 / 256, 256, 0, stream>>>(QKVb, AOb);

    wo_ln_kernel<<<NROW / 32, 256, 0, stream>>>(AOb, WOT, bo, x, g2, b2, Tf, tn2);

    w1_kernel<<<(NROW / 64) * 8, 256, 0, stream>>>(tn2, W1T, bf1, Hb);

    gemm_kernel<1024, 2, 4><<<(NROW / 64) * 4, 256, 0, stream>>>(Hb, W2T, bf2, Tf, (float*)d_out, 256);
}

// Round 15
// 71.892 us; speedup vs baseline: 1.1292x; 1.0308x over previous
//
#include <hip/hip_runtime.h>

typedef __bf16 bf16x8 __attribute__((ext_vector_type(8)));
typedef float f32x4 __attribute__((ext_vector_type(4)));

#define DEV static __device__ __forceinline__

DEV unsigned short f2b(float f){
    unsigned int u = __float_as_uint(f);
    u += 0x7fffu + ((u >> 16) & 1u);
    return (unsigned short)(u >> 16);
}
DEV float b2f(unsigned short h){ return __uint_as_float(((unsigned int)h) << 16); }
DEV float blo(unsigned int u){ return __uint_as_float(u << 16); }
DEV float bhi(unsigned int u){ return __uint_as_float(u & 0xffff0000u); }
DEV float gelu_f(float x){ return 0.5f * x * (1.0f + erff(x * 0.7071067811865476f)); }

// async global->LDS, 16B per lane, wave-uniform LDS base (HW adds lane*16).
DEV void gload16(const unsigned short* g, unsigned short* l){
    __builtin_amdgcn_global_load_lds(
        (const __attribute__((address_space(1))) void*)g,
        (__attribute__((address_space(3))) void*)l, 16, 0, 0);
}

// ---------------------------------------------------------------- constants
static constexpr int NROW = 8192;   // B*D*H*W = 2*16*16*16
static constexpr int C    = 256;
static constexpr int F    = 1024;
static constexpr float ATT_SCALE = 0.17677669529663688f;   // 1/sqrt(32)

// ---------------------------------------------------------------- prep + LN1
__global__ __launch_bounds__(256)
void prep_ln_kernel(const float* __restrict__ Wq, const float* __restrict__ Wk,
                    const float* __restrict__ Wv, const float* __restrict__ Wo,
                    const float* __restrict__ W1, const float* __restrict__ W2,
                    const float* __restrict__ bq, const float* __restrict__ bk,
                    const float* __restrict__ bv,
                    unsigned short* __restrict__ WQT, unsigned short* __restrict__ WKT,
                    unsigned short* __restrict__ WVT, unsigned short* __restrict__ WOT,
                    unsigned short* __restrict__ W1T, unsigned short* __restrict__ W2T,
                    float* __restrict__ bqkv,
                    const float* __restrict__ x, const float* __restrict__ g1,
                    const float* __restrict__ b1,
                    unsigned short* __restrict__ tn, unsigned short* __restrict__ xb)
{
    const int tid = threadIdx.x;
    if (blockIdx.x < 192) {
        __shared__ unsigned short T[64][66];
        const int t = blockIdx.x;
        const float* src; unsigned short* dst;
        int ldw, ldt, r0, c0; float sc = 1.0f;
        if (t < 64) {                       // 4 square 256x256 mats, 16 tiles each
            const int m = t >> 4, sub = t & 15;
            src = (m == 0) ? Wq : (m == 1) ? Wk : (m == 2) ? Wv : Wo;
            dst = (m == 0) ? WQT : (m == 1) ? WKT : (m == 2) ? WVT : WOT;
            if (m == 0) sc = ATT_SCALE;
            ldw = 256; ldt = 256;
            r0 = (sub >> 2) * 64; c0 = (sub & 3) * 64;
        } else if (t < 128) {               // W1: 256x1024 -> W1T [1024][256]
            const int sub = t - 64;
            src = W1; dst = W1T; ldw = 1024; ldt = 256;
            r0 = (sub >> 4) * 64; c0 = (sub & 15) * 64;
        } else {                            // W2: 1024x256 -> W2T [256][1024]
            const int sub = t - 128;
            src = W2; dst = W2T; ldw = 256; ldt = 1024;
            r0 = (sub >> 2) * 64; c0 = (sub & 3) * 64;
        }
        #pragma unroll
        for (int i = 0; i < 16; ++i) {
            const int rl = i * 4 + (tid >> 6), cl = tid & 63;
            T[rl][cl] = f2b(src[(size_t)(r0 + rl) * ldw + c0 + cl] * sc);
        }
        __syncthreads();
        #pragma unroll
        for (int j = 0; j < 16; ++j) {
            const int cl = j * 4 + (tid >> 6), rl = tid & 63;
            dst[(size_t)(c0 + cl) * ldt + r0 + rl] = T[rl][cl];
        }
    } else if (blockIdx.x == 192) {
        #pragma unroll
        for (int i = 0; i < 3; ++i) {
            const int v = i * 256 + tid;
            bqkv[v] = (v < 256) ? bq[v] * ATT_SCALE
                    : (v < 512) ? bk[v - 256] : bv[v - 512];
        }
    } else {
        const int row  = (blockIdx.x - 193) * 4 + (tid >> 6);
        const int lane = tid & 63;
        float4 v = ((const float4*)(x + (size_t)row * C))[lane];
        float s = v.x + v.y + v.z + v.w;
        #pragma unroll
        for (int m = 32; m >= 1; m >>= 1) s += __shfl_xor(s, m);
        const float mean = s * (1.0f / 256.0f);
        const float d0 = v.x - mean, d1 = v.y - mean, d2 = v.z - mean, d3 = v.w - mean;
        float s2 = d0 * d0 + d1 * d1 + d2 * d2 + d3 * d3;
        #pragma unroll
        for (int m = 32; m >= 1; m >>= 1) s2 += __shfl_xor(s2, m);
        const float rstd = rsqrtf(s2 * (1.0f / 256.0f) + 1e-5f);
        float4 gg = ((const float4*)g1)[lane];
        float4 bb = ((const float4*)b1)[lane];
        ushort4 o = { f2b(d0 * rstd * gg.x + bb.x), f2b(d1 * rstd * gg.y + bb.y),
                      f2b(d2 * rstd * gg.z + bb.z), f2b(d3 * rstd * gg.w + bb.w) };
        ((ushort4*)(tn + (size_t)row * C))[lane] = o;
        ushort4 xo = { f2b(v.x), f2b(v.y), f2b(v.z), f2b(v.w) };
        ((ushort4*)(xb + (size_t)row * C))[lane] = xo;
    }
}

// ---------------------------------------------------------------- 64x64 GEMM
// (kept for W2: K=1024, N=256)
template<int K, int MODE>
DEV void gemm_body(const unsigned short* __restrict__ A, int m0,
                   const unsigned short* __restrict__ BTt,
                   const float* __restrict__ biast,
                   const float* __restrict__ res, void* __restrict__ outp,
                   int ldo, int ocol0,
                   unsigned short (&As)[2][4096], unsigned short (&Bs)[2][4096])
{
    constexpr int BK = 64, NKT = K / BK;
    const int tid  = threadIdx.x;
    const int lane = tid & 63, wid = tid >> 6;
    const int srow = tid >> 3;                    // 0..31
    const int schk = (tid & 7) ^ (srow & 7);      // inverse-swizzled src chunk

    const unsigned short* Ag = A   + (size_t)(m0 + srow) * K + schk * 8;
    const unsigned short* Bg = BTt + (size_t)srow        * K + schk * 8;

    const int wbase = __builtin_amdgcn_readfirstlane(wid) * 512;

    gload16(Ag,          &As[0][wbase]);
    gload16(Ag + 32 * K, &As[0][wbase + 2048]);
    gload16(Bg,          &Bs[0][wbase]);
    gload16(Bg + 32 * K, &Bs[0][wbase + 2048]);
    __syncthreads();

    f32x4 acc[4] = {};
    const int lr = lane & 15, lk = lane >> 4;
    const int sw = lr & 7;

    for (int kt = 0; kt < NKT; ++kt) {
        if (kt + 1 < NKT) {
            const int nb = (kt + 1) & 1;
            gload16(Ag + (kt + 1) * BK,          &As[nb][wbase]);
            gload16(Ag + 32 * K + (kt + 1) * BK, &As[nb][wbase + 2048]);
            gload16(Bg + (kt + 1) * BK,          &Bs[nb][wbase]);
            gload16(Bg + 32 * K + (kt + 1) * BK, &Bs[nb][wbase + 2048]);
        }
        const unsigned short* as = As[kt & 1];
        const unsigned short* bs = Bs[kt & 1];
        #pragma unroll
        for (int s = 0; s < 2; ++s) {
            const int c16 = (s * 4 + lk) ^ sw;
            bf16x8 bfr = *reinterpret_cast<const bf16x8*>(&bs[(wid * 16 + lr) * 64 + c16 * 8]);
            #pragma unroll
            for (int m = 0; m < 4; ++m) {
                bf16x8 afr = *reinterpret_cast<const bf16x8*>(&as[(m * 16 + lr) * 64 + c16 * 8]);
                acc[m] = __builtin_amdgcn_mfma_f32_16x16x32_bf16(afr, bfr, acc[m], 0, 0, 0);
            }
        }
        if (kt + 1 < NKT) __syncthreads();
    }

    const int col  = ocol0 + wid * 16 + lr;
    const float bcol = biast[wid * 16 + lr];
    #pragma unroll
    for (int m = 0; m < 4; ++m) {
        #pragma unroll
        for (int r = 0; r < 4; ++r) {
            const int row = m0 + m * 16 + lk * 4 + r;
            float v = acc[m][r] + bcol;
            if (MODE == 0) {
                ((unsigned short*)outp)[(size_t)row * ldo + col] = f2b(v);
            } else if (MODE == 1) {
                ((unsigned short*)outp)[(size_t)row * ldo + col] = f2b(gelu_f(v));
            } else {
                v += res[(size_t)row * ldo + col];
                ((float*)outp)[(size_t)row * ldo + col] = v;
            }
        }
    }
}

// ---------------------------------------------------------------- 128x128 GEMM
// 4 waves in 2x2 quadrants; wave owns 64x64 (acc[4][4], 64 VGPR). BK=64 dbuf,
// MFMA:ds_read = 2:1 (vs 1.33 at 64x128). ALL gload_lds LDS destinations are
// wave-uniform (readfirstlane base + literal offsets) — round-7's divergent
// per-lane pointer is the suspected waterfall that stalled this tile size.
template<int K, int MODE>
DEV void gemm128_body(const unsigned short* __restrict__ A, int m0,
                      const unsigned short* __restrict__ BTt,  // BT + n0*K
                      const float* __restrict__ biast,
                      void* __restrict__ outp, int ldo, int ocol0,
                      unsigned short (&As)[2][8192], unsigned short (&Bs)[2][8192])
{
    constexpr int BK = 64, NKT = K / BK;
    const int tid  = threadIdx.x;
    const int lane = tid & 63, wid = tid >> 6;
    const int srow = tid >> 3;                    // 0..31 (+32*i per gload)
    const int schk = (tid & 7) ^ (srow & 7);      // (srow+32i)&7 == srow&7

    const unsigned short* Ag = A   + (size_t)(m0 + srow) * K + schk * 8;
    const unsigned short* Bg = BTt + (size_t)srow        * K + schk * 8;

    const int wbase = __builtin_amdgcn_readfirstlane(wid) * 512;

    #pragma unroll
    for (int i = 0; i < 4; ++i) {
        gload16(Ag + (size_t)(32 * i) * K, &As[0][i * 2048 + wbase]);
        gload16(Bg + (size_t)(32 * i) * K, &Bs[0][i * 2048 + wbase]);
    }
    __syncthreads();

    f32x4 acc[4][4] = {};
    const int lr = lane & 15, lk = lane >> 4;
    const int sw = lr & 7;
    const int wr = (wid >> 1) * 64, wc = (wid & 1) * 64;

    for (int kt = 0; kt < NKT; ++kt) {
        if (kt + 1 < NKT) {
            const int nb = (kt + 1) & 1;
            #pragma unroll
            for (int i = 0; i < 4; ++i) {
                gload16(Ag + (size_t)(32 * i) * K + (kt + 1) * BK, &As[nb][i * 2048 + wbase]);
                gload16(Bg + (size_t)(32 * i) * K + (kt + 1) * BK, &Bs[nb][i * 2048 + wbase]);
            }
        }
        const unsigned short* as = As[kt & 1];
        const unsigned short* bs = Bs[kt & 1];
        #pragma unroll
        for (int ks = 0; ks < 2; ++ks) {
            const int c16 = (ks * 4 + lk) ^ sw;
            bf16x8 af[4], bf[4];
            #pragma unroll
            for (int m = 0; m < 4; ++m)
                af[m] = *reinterpret_cast<const bf16x8*>(&as[(wr + m * 16 + lr) * 64 + c16 * 8]);
            #pragma unroll
            for (int n = 0; n < 4; ++n)
                bf[n] = *reinterpret_cast<const bf16x8*>(&bs[(wc + n * 16 + lr) * 64 + c16 * 8]);
            #pragma unroll
            for (int m = 0; m < 4; ++m)
                #pragma unroll
                for (int n = 0; n < 4; ++n)
                    acc[m][n] = __builtin_amdgcn_mfma_f32_16x16x32_bf16(af[m], bf[n], acc[m][n], 0, 0, 0);
        }
        if (kt + 1 < NKT) __syncthreads();
    }

    #pragma unroll
    for (int n = 0; n < 4; ++n) {
        const int cl  = wc + n * 16 + lr;
        const int col = ocol0 + cl;
        const float bcol = biast[cl];
        #pragma unroll
        for (int m = 0; m < 4; ++m) {
            #pragma unroll
            for (int r = 0; r < 4; ++r) {
                const int row = m0 + wr + m * 16 + lk * 4 + r;
                const float v = acc[m][n][r] + bcol;
                if (MODE == 0) {
                    ((unsigned short*)outp)[(size_t)row * ldo + col] = f2b(v);
                } else {
                    ((unsigned short*)outp)[(size_t)row * ldo + col] = f2b(gelu_f(v));
                }
            }
        }
    }
}

// XCD-swizzled 1D-grid tile maps, column-fastest (T1). Requires nwg % 8 == 0.
template<int NC, int TS>
DEV void tile_map(int& m0, int& n0){
    const int nwg = gridDim.x;
    const int lin = blockIdx.x;
    const int tile = (lin & 7) * (nwg >> 3) + (lin >> 3);
    m0 = (tile / NC) * TS;
    n0 = (tile % NC) * TS;
}

// Fused Q/K/V GEMM at 128x128: N=768, A = tn for Q cols (n0<256), xb for K/V.
__global__ __launch_bounds__(256, 2)
void qkv_kernel(const unsigned short* __restrict__ tn,
                const unsigned short* __restrict__ xb,
                const unsigned short* __restrict__ WT,    // [768][256]
                const float* __restrict__ bqkv,           // [768]
                unsigned short* __restrict__ QKV)         // [8192][768]
{
    __shared__ unsigned short As[2][8192], Bs[2][8192];
    int m0, n0; tile_map<6, 128>(m0, n0);
    const unsigned short* A = (n0 < 256) ? tn : xb;
    gemm128_body<256, 0>(A, m0, WT + (size_t)n0 * 256,
                         bqkv + n0, QKV, 768, n0, As, Bs);
}

// W1 GEMM at 128x128 with GELU epilogue.
__global__ __launch_bounds__(256, 2)
void w1_kernel(const unsigned short* __restrict__ tn2,
               const unsigned short* __restrict__ W1T,    // [1024][256]
               const float* __restrict__ bf1,
               unsigned short* __restrict__ Hb)           // [8192][1024]
{
    __shared__ unsigned short As[2][8192], Bs[2][8192];
    int m0, n0; tile_map<8, 128>(m0, n0);
    gemm128_body<256, 1>(tn2, m0, W1T + (size_t)n0 * 256,
                         bf1 + n0, Hb, 1024, n0, As, Bs);
}

template<int K, int MODE, int NC>
__global__ __launch_bounds__(256)
void gemm_kernel(const unsigned short* __restrict__ A,
                 const unsigned short* __restrict__ BT,
                 const float* __restrict__ bias,
                 const float* __restrict__ res,
                 void* __restrict__ outp, int ldo)
{
    __shared__ unsigned short As[2][4096], Bs[2][4096];
    int m0, n0; tile_map<NC, 64>(m0, n0);
    gemm_body<K, MODE>(A, m0, BT + (size_t)n0 * K,
                       bias + n0, res, outp, ldo, n0, As, Bs);
}

// ---------------------------------------------------- Wo GEMM + residual + LN2
// Tile 32 x 256 (FULL output width per block -> block owns complete rows, so
// LN2 fuses in): t = AO@Wo + bo + x, Tf = t (f32), tn2 = LN(t) (bf16).
__global__ __launch_bounds__(256, 2)
void wo_ln_kernel(const unsigned short* __restrict__ AOb,
                  const unsigned short* __restrict__ WOT,    // [256][256]
                  const float* __restrict__ bo,
                  const float* __restrict__ x,               // residual f32
                  const float* __restrict__ g2, const float* __restrict__ b2,
                  float* __restrict__ Tf,
                  unsigned short* __restrict__ tn2)
{
    __shared__ unsigned short As[2][2048];     // 32 x 64
    __shared__ unsigned short Bs[2][16384];    // 256 x 64
    __shared__ float2 red[4][32];              // [wave][row] {sum, sumsq}

    const int lin = blockIdx.x;
    const int m0  = ((lin & 7) * (gridDim.x >> 3) + (lin >> 3)) * 32;

    const int tid  = threadIdx.x;
    const int lane = tid & 63, wid = tid >> 6;
    const int srow = tid >> 3;                 // 0..31
    const int schk = (tid & 7) ^ (srow & 7);

    const unsigned short* Ag = AOb + (size_t)(m0 + srow) * 256 + schk * 8;
    const unsigned short* Bg = WOT + (size_t)srow        * 256 + schk * 8;

    const int wbase = __builtin_amdgcn_readfirstlane(wid) * 512;

    gload16(Ag, &As[0][wbase]);
    #pragma unroll
    for (int i = 0; i < 8; ++i)
        gload16(Bg + (size_t)(32 * i) * 256, &Bs[0][i * 2048 + wbase]);
    __syncthreads();

    f32x4 acc[2][4] = {};
    const int lr = lane & 15, lk = lane >> 4;
    const int sw = lr & 7;
    const int wc = wid * 64;                   // wave's col base

    for (int kt = 0; kt < 4; ++kt) {
        if (kt < 3) {
            const int nb = (kt + 1) & 1;
            gload16(Ag + (kt + 1) * 64, &As[nb][wbase]);
            #pragma unroll
            for (int i = 0; i < 8; ++i)
                gload16(Bg + (size_t)(32 * i) * 256 + (kt + 1) * 64, &Bs[nb][i * 2048 + wbase]);
        }
        const unsigned short* as = As[kt & 1];
        const unsigned short* bs = Bs[kt & 1];
        #pragma unroll
        for (int ks = 0; ks < 2; ++ks) {
            const int c16 = (ks * 4 + lk) ^ sw;
            bf16x8 af[2], bf[4];
            #pragma unroll
            for (int m = 0; m < 2; ++m)
                af[m] = *reinterpret_cast<const bf16x8*>(&as[(m * 16 + lr) * 64 + c16 * 8]);
            #pragma unroll
            for (int n = 0; n < 4; ++n)
                bf[n] = *reinterpret_cast<const bf16x8*>(&bs[(wc + n * 16 + lr) * 64 + c16 * 8]);
            #pragma unroll
            for (int m = 0; m < 2; ++m)
                #pragma unroll
                for (int n = 0; n < 4; ++n)
                    acc[m][n] = __builtin_amdgcn_mfma_f32_16x16x32_bf16(af[m], bf[n], acc[m][n], 0, 0, 0);
        }
        if (kt < 3) __syncthreads();
    }

    // epilogue: v = acc + bo + x
    #pragma unroll
    for (int n = 0; n < 4; ++n) {
        const int col = wc + n * 16 + lr;
        const float bcol = bo[col];
        #pragma unroll
        for (int m = 0; m < 2; ++m) {
            #pragma unroll
            for (int r = 0; r < 4; ++r) {
                const int row = m0 + m * 16 + lk * 4 + r;
                acc[m][n][r] += bcol + x[(size_t)row * 256 + col];
            }
        }
    }

    // per-row partial sums over the wave's 64-col slice
    float s1[2][4], s2[2][4];
    #pragma unroll
    for (int m = 0; m < 2; ++m)
        #pragma unroll
        for (int r = 0; r < 4; ++r) {
            float a = 0.f, b = 0.f;
            #pragma unroll
            for (int n = 0; n < 4; ++n) { const float v = acc[m][n][r]; a += v; b += v * v; }
            s1[m][r] = a; s2[m][r] = b;
        }
    #pragma unroll
    for (int mask = 1; mask <= 8; mask <<= 1)
        #pragma unroll
        for (int m = 0; m < 2; ++m)
            #pragma unroll
            for (int r = 0; r < 4; ++r) {
                s1[m][r] += __shfl_xor(s1[m][r], mask);
                s2[m][r] += __shfl_xor(s2[m][r], mask);
            }
    if (lr == 0) {
        #pragma unroll
        for (int m = 0; m < 2; ++m)
            #pragma unroll
            for (int r = 0; r < 4; ++r)
                red[wid][m * 16 + lk * 4 + r] = make_float2(s1[m][r], s2[m][r]);
    }
    __syncthreads();

    float mean[2][4], rstd[2][4];
    #pragma unroll
    for (int m = 0; m < 2; ++m)
        #pragma unroll
        for (int r = 0; r < 4; ++r) {
            const int rl = m * 16 + lk * 4 + r;
            float a = 0.f, b = 0.f;
            #pragma unroll
            for (int w4 = 0; w4 < 4; ++w4) { const float2 p = red[w4][rl]; a += p.x; b += p.y; }
            const float mu = a * (1.0f / 256.0f);
            mean[m][r] = mu;
            rstd[m][r] = rsqrtf(b * (1.0f / 256.0f) - mu * mu + 1e-5f);
        }

    #pragma unroll
    for (int n = 0; n < 4; ++n) {
        const int col = wc + n * 16 + lr;
        const float gc = g2[col], bc = b2[col];
        #pragma unroll
        for (int m = 0; m < 2; ++m) {
            #pragma unroll
            for (int r = 0; r < 4; ++r) {
                const int row = m0 + m * 16 + lk * 4 + r;
                const float v = acc[m][n][r];
                Tf[(size_t)row * 256 + col] = v;
                tn2[(size_t)row * 256 + col] =
                    f2b((v - mean[m][r]) * rstd[m][r] * gc + bc);
            }
        }
    }
}

// ---------------------------------------------------------------- attention
// Thread = (voxel, head, quarter), 16 waves/CU, online softmax per 9-group,
// K+V loads hoisted (18 outstanding), XCD-slab block mapping.
// QKV layout: [NROW][768] bf16: Q (pre-scaled) 0..255, K 256..511, V 512..767.
DEV float dot8(uint4 u, const float* q){
    float s;
    s = q[0] * blo(u.x);          s = fmaf(q[1], bhi(u.x), s);
    s = fmaf(q[2], blo(u.y), s);  s = fmaf(q[3], bhi(u.y), s);
    s = fmaf(q[4], blo(u.z), s);  s = fmaf(q[5], bhi(u.z), s);
    s = fmaf(q[6], blo(u.w), s);  s = fmaf(q[7], bhi(u.w), s);
    return s;
}

__global__ __launch_bounds__(256, 4)
void attn_kernel(const unsigned short* __restrict__ QKV,
                 unsigned short* __restrict__ AO)
{
    const int lin = blockIdx.x;
    const int sb  = (lin & 7) * (gridDim.x >> 3) + (lin >> 3);   // XCD slab map
    const int t   = sb * 256 + threadIdx.x;
    const int vox = t >> 5;                 // 32 threads per voxel
    const int ch  = (t & 31) * 8;           // head*32 + quarter*8
    const int d = (vox >> 8) & 15, h = (vox >> 4) & 15, w = vox & 15;

    float q[8];
    {
        uint4 u = *reinterpret_cast<const uint4*>(&QKV[(size_t)vox * 768 + ch]);
        q[0]=blo(u.x); q[1]=bhi(u.x); q[2]=blo(u.y); q[3]=bhi(u.y);
        q[4]=blo(u.z); q[5]=bhi(u.z); q[6]=blo(u.w); q[7]=bhi(u.w);
    }

    float mrun = -1e30f, z = 0.0f;
    float acc[8] = {};

    #pragma unroll
    for (int g = 0; g < 3; ++g) {
        const int di = g - 1;
        const int nd = d + di;
        unsigned vm = 0;
        uint4 ku[9], vu[9];
        #pragma unroll
        for (int j = 0; j < 9; ++j) {
            const int hi2 = j / 3 - 1, wi = j % 3 - 1;
            const int nh = h + hi2, nw = w + wi;
            const bool valid = !(di == 0 && hi2 == 0 && wi == 0) &&
                               ((unsigned)nd < 16u) && ((unsigned)nh < 16u) &&
                               ((unsigned)nw < 16u);
            const int r = valid ? ((vox & 4096) | (nd << 8) | (nh << 4) | nw) : vox;
            vm |= (unsigned)valid << j;
            const unsigned short* base = &QKV[(size_t)r * 768 + 256 + ch];
            ku[j] = *reinterpret_cast<const uint4*>(base);
            vu[j] = *reinterpret_cast<const uint4*>(base + 256);
        }

        float s9[9];
        #pragma unroll
        for (int j = 0; j < 9; ++j) {
            float s = dot8(ku[j], q);
            s += __shfl_xor(s, 1);          // quad-perm DPP (VALU pipe)
            s += __shfl_xor(s, 2);
            s9[j] = ((vm >> j) & 1u) ? s : -INFINITY;
        }

        float gm = s9[0];
        #pragma unroll
        for (int j = 1; j < 9; ++j) gm = fmaxf(gm, s9[j]);
        const float nm = fmaxf(mrun, gm);   // finite always
        const float rs = __expf(mrun - nm);
        mrun = nm;
        z *= rs;
        #pragma unroll
        for (int i = 0; i < 8; ++i) acc[i] *= rs;

        #pragma unroll
        for (int j = 0; j < 9; ++j) {
            const float p = __expf(s9[j] - nm);   // -inf -> exactly 0
            z += p;
            const uint4 u = vu[j];
            acc[0] = fmaf(p, blo(u.x), acc[0]); acc[1] = fmaf(p, bhi(u.x), acc[1]);
            acc[2] = fmaf(p, blo(u.y), acc[2]); acc[3] = fmaf(p, bhi(u.y), acc[3]);
            acc[4] = fmaf(p, blo(u.z), acc[4]); acc[5] = fmaf(p, bhi(u.z), acc[5]);
            acc[6] = fmaf(p, blo(u.w), acc[6]); acc[7] = fmaf(p, bhi(u.w), acc[7]);
        }
    }

    const float inv = 1.0f / z;
    uint4 o;
    o.x = (unsigned)f2b(acc[0] * inv) | ((unsigned)f2b(acc[1] * inv) << 16);
    o.y = (unsigned)f2b(acc[2] * inv) | ((unsigned)f2b(acc[3] * inv) << 16);
    o.z = (unsigned)f2b(acc[4] * inv) | ((unsigned)f2b(acc[5] * inv) << 16);
    o.w = (unsigned)f2b(acc[6] * inv) | ((unsigned)f2b(acc[7] * inv) << 16);
    *reinterpret_cast<uint4*>(&AO[(size_t)vox * C + ch]) = o;
}

// ---------------------------------------------------------------- launch
extern "C" void kernel_launch(void* const* d_in, const int* in_sizes, int n_in,
                              void* d_out, int out_size, void* d_ws, size_t ws_size,
                              hipStream_t stream)
{
    const float* x   = (const float*)d_in[0];
    const float* Wq  = (const float*)d_in[1];
    const float* bq  = (const float*)d_in[2];
    const float* Wk  = (const float*)d_in[3];
    const float* bk  = (const float*)d_in[4];
    const float* Wv  = (const float*)d_in[5];
    const float* bv  = (const float*)d_in[6];
    const float* Wo  = (const float*)d_in[7];
    const float* bo  = (const float*)d_in[8];
    const float* g1  = (const float*)d_in[9];
    const float* b1  = (const float*)d_in[10];
    const float* g2  = (const float*)d_in[11];
    const float* b2  = (const float*)d_in[12];
    const float* W1  = (const float*)d_in[13];
    const float* bf1 = (const float*)d_in[14];
    const float* W2  = (const float*)d_in[15];
    const float* bf2 = (const float*)d_in[16];

    char* ws = (char*)d_ws;
    size_t o = 0;
    unsigned short* WQT = (unsigned short*)(ws + o); o += (size_t)256 * 256 * 2;   // [768][256] with WKT/WVT
    unsigned short* WKT = (unsigned short*)(ws + o); o += (size_t)256 * 256 * 2;
    unsigned short* WVT = (unsigned short*)(ws + o); o += (size_t)256 * 256 * 2;
    unsigned short* WOT = (unsigned short*)(ws + o); o += (size_t)256 * 256 * 2;
    unsigned short* W1T = (unsigned short*)(ws + o); o += (size_t)256 * 1024 * 2;
    unsigned short* W2T = (unsigned short*)(ws + o); o += (size_t)1024 * 256 * 2;
    float*          bqkv= (float*)(ws + o);          o += (size_t)768 * 4;
    unsigned short* tn  = (unsigned short*)(ws + o); o += (size_t)NROW * C * 2;
    unsigned short* xb  = (unsigned short*)(ws + o); o += (size_t)NROW * C * 2;
    unsigned short* QKVb= (unsigned short*)(ws + o); o += (size_t)NROW * 768 * 2;
    unsigned short* AOb = (unsigned short*)(ws + o); o += (size_t)NROW * C * 2;
    float*          Tf  = (float*)(ws + o);          o += (size_t)NROW * C * 4;
    unsigned short* tn2 = (unsigned short*)(ws + o); o += (size_t)NROW * C * 2;
    unsigned short* Hb  = (unsigned short*)(ws + o); o += (size_t)NROW * F * 2;

    prep_ln_kernel<<<193 + NROW / 4, 256, 0, stream>>>(Wq, Wk, Wv, Wo, W1, W2, bq, bk, bv,
                                                       WQT, WKT, WVT, WOT, W1T, W2T, bqkv,
                                                       x, g1, b1, tn, xb);

    qkv_kernel<<<(NROW / 128) * 6, 256, 0, stream>>>(tn, xb, WQT, bqkv, QKVb);

    attn_kernel<<<NROW * 32 / 256, 256, 0, stream>>>(QKVb, AOb);

    wo_ln_kernel<<<NROW / 32, 256, 0, stream>>>(AOb, WOT, bo, x, g2, b2, Tf, tn2);

    w1_kernel<<<(NROW / 128) * 8, 256, 0, stream>>>(tn2, W1T, bf1, Hb);

    gemm_kernel<1024, 2, 4><<<(NROW / 64) * 4, 256, 0, stream>>>(Hb, W2T, bf2, Tf, (float*)d_out, 256);
}